// Round 1
// baseline (24927.515 us; speedup 1.0000x reference)
//
#include <hip/hip_runtime.h>
#include <cfloat>
#include <cmath>

// ---------------------------------------------------------------------------
// VQ-VAE forward, fp32 direct-conv baseline (round 0: correctness first).
// Shapes: x (2,3,64^3); enc -> latent (2,256,8^3); VQ K=1024 CD=256;
// dec (ConvTranspose3d k4 s2 p1 x3) -> (2,64,64^3); final conv k4 s1 p0 + tanh
// -> (2,3,61^3). Outputs: recon (1361886 f32) then quantized_idx (1024) as f32.
// ---------------------------------------------------------------------------

// Conv3d k=4, stride=2, pad=1, optional relu. x:(N,Cin,Din^3) w:(Cout,Cin,4,4,4)
__global__ void conv3d_s2p1k4(const float* __restrict__ x, const float* __restrict__ w,
                              const float* __restrict__ bias, float* __restrict__ y,
                              int N, int Cin, int Cout, int Din, int Dout, int relu)
{
    int total = N * Cout * Dout * Dout * Dout;
    int idx = blockIdx.x * blockDim.x + threadIdx.x;
    if (idx >= total) return;
    int ow = idx % Dout; int t = idx / Dout;
    int oh = t % Dout; t /= Dout;
    int od = t % Dout; t /= Dout;
    int co = t % Cout; int n = t / Cout;

    float sum = bias[co];
    int id0 = od * 2 - 1, ih0 = oh * 2 - 1, iw0 = ow * 2 - 1;
    const long dsz = (long)Din * Din * Din;
    const float* xb = x + (long)n * Cin * dsz;
    const float* wb = w + (long)co * Cin * 64;
    for (int ci = 0; ci < Cin; ++ci) {
        const float* xc = xb + ci * dsz;
        const float* wc = wb + ci * 64;
        for (int kd = 0; kd < 4; ++kd) {
            int id = id0 + kd;
            if ((unsigned)id >= (unsigned)Din) continue;
            for (int kh = 0; kh < 4; ++kh) {
                int ih = ih0 + kh;
                if ((unsigned)ih >= (unsigned)Din) continue;
                const float* xr = xc + ((long)id * Din + ih) * Din;
                const float* wr = wc + kd * 16 + kh * 4;
                #pragma unroll
                for (int kw = 0; kw < 4; ++kw) {
                    int iw = iw0 + kw;
                    if ((unsigned)iw < (unsigned)Din) sum = fmaf(xr[iw], wr[kw], sum);
                }
            }
        }
    }
    if (relu) sum = fmaxf(sum, 0.0f);
    y[idx] = sum;
}

// 1x1 conv: x:(N,Cin,Sp) w:(Cout,Cin) -> y:(N,Cout,Sp). No activation.
__global__ void conv1x1(const float* __restrict__ x, const float* __restrict__ w,
                        const float* __restrict__ bias, float* __restrict__ y,
                        int N, int Cin, int Cout, int Sp)
{
    int total = N * Cout * Sp;
    int idx = blockIdx.x * blockDim.x + threadIdx.x;
    if (idx >= total) return;
    int s = idx % Sp;
    int co = (idx / Sp) % Cout;
    int n = idx / (Sp * Cout);
    float sum = bias[co];
    const float* xb = x + (long)n * Cin * Sp + s;
    const float* wb = w + (long)co * Cin;
    for (int ci = 0; ci < Cin; ++ci)
        sum = fmaf(xb[(long)ci * Sp], wb[ci], sum);
    y[idx] = sum;
}

// Codebook row squared norms. grid = K blocks of 64 lanes.
__global__ void codenorm_kernel(const float* __restrict__ cb, float* __restrict__ norms)
{
    int k = blockIdx.x;
    int lane = threadIdx.x;
    float s = 0.0f;
    const float* row = cb + (long)k * 256;
    for (int d = lane; d < 256; d += 64) { float v = row[d]; s = fmaf(v, v, s); }
    for (int off = 32; off > 0; off >>= 1) s += __shfl_down(s, off);
    if (lane == 0) norms[k] = s;
}

// VQ: one block (256 thr) per row r in [0, B*N). lat rows are contiguous
// 256-float chunks of the channel-first latent (raw torch .view semantics).
// Writes q in channel-first (B, CD, 512) layout and idx as float.
__global__ void vq_kernel(const float* __restrict__ lat, const float* __restrict__ cb,
                          const float* __restrict__ norms, float* __restrict__ q,
                          float* __restrict__ idx_out)
{
    __shared__ float row[256];
    __shared__ float s_best[256];
    __shared__ int   s_bidx[256];
    int r = blockIdx.x;       // r = b*512 + n
    int t = threadIdx.x;
    const float* lr = lat + (long)r * 256;
    row[t] = lr[t];
    __syncthreads();

    // ||lat||^2 (constant per row; kept for numerical fidelity to reference)
    float latn = 0.0f;
    for (int d = 0; d < 256; ++d) latn = fmaf(row[d], row[d], latn);

    float best = FLT_MAX;
    int bidx = 0x7fffffff;
    for (int j = 0; j < 4; ++j) {
        int k = t + 256 * j;
        const float* cr = cb + (long)k * 256;
        float dot = 0.0f;
        for (int d = 0; d < 256; ++d) dot = fmaf(row[d], cr[d], dot);
        float sc = latn - 2.0f * dot + norms[k];
        if (sc < best || (sc == best && k < bidx)) { best = sc; bidx = k; }
    }
    s_best[t] = best; s_bidx[t] = bidx;
    __syncthreads();
    for (int off = 128; off > 0; off >>= 1) {
        if (t < off) {
            float o = s_best[t + off]; int oi = s_bidx[t + off];
            if (o < s_best[t] || (o == s_best[t] && oi < s_bidx[t])) {
                s_best[t] = o; s_bidx[t] = oi;
            }
        }
        __syncthreads();
    }
    int bk = s_bidx[0];
    int b = r >> 9, n = r & 511;
    // q[b][cd=t][spatial=n], spatial stride 1, cd stride 512
    q[(long)b * 131072 + (long)t * 512 + n] = cb[(long)bk * 256 + t];
    if (t == 0) idx_out[r] = (float)bk;
}

// ConvTranspose3d k=4, stride=2, pad=1 as GATHER, single batch.
// x:(Cin,Din^3) w:(Cin,Cout,4,4,4) y:(Cout,Dout^3), Dout=2*Din. Optional relu.
// Valid taps: kd ≡ (od+1) mod 2, id=(od+1-kd)/2 in [0,Din).
__global__ void convt3d_s2p1k4(const float* __restrict__ x, const float* __restrict__ w,
                               const float* __restrict__ bias, float* __restrict__ y,
                               int Cin, int Cout, int Din, int Dout, int relu)
{
    int total = Cout * Dout * Dout * Dout;
    int idx = blockIdx.x * blockDim.x + threadIdx.x;
    if (idx >= total) return;
    int ow = idx % Dout; int t = idx / Dout;
    int oh = t % Dout; t /= Dout;
    int od = t % Dout; int co = t / Dout;

    float sum = bias[co];
    int pd = (od + 1) & 1, ph = (oh + 1) & 1, pw = (ow + 1) & 1;
    const long dsz = (long)Din * Din * Din;
    const long wstride = (long)Cout * 64;

    for (int a = 0; a < 2; ++a) {
        int kd = pd + 2 * a; int id = (od + 1 - kd) >> 1;
        if ((unsigned)id >= (unsigned)Din) continue;
        for (int b2 = 0; b2 < 2; ++b2) {
            int kh = ph + 2 * b2; int ih = (oh + 1 - kh) >> 1;
            if ((unsigned)ih >= (unsigned)Din) continue;
            for (int c2 = 0; c2 < 2; ++c2) {
                int kw = pw + 2 * c2; int iw = (ow + 1 - kw) >> 1;
                if ((unsigned)iw >= (unsigned)Din) continue;
                int koff = kd * 16 + kh * 4 + kw;
                const float* xr = x + ((long)id * Din + ih) * Din + iw;
                const float* wr = w + (long)co * 64 + koff;
                float s2 = 0.0f;
                for (int ci = 0; ci < Cin; ++ci)
                    s2 = fmaf(xr[ci * dsz], wr[ci * wstride], s2);
                sum += s2;
            }
        }
    }
    if (relu) sum = fmaxf(sum, 0.0f);
    y[idx] = sum;
}

// Final conv k=4, stride=1, pad=0, tanh. Single batch.
// x:(Cin,Din^3) w:(Cout,Cin,4,4,4) y:(Cout,Dout^3), Dout=Din-3.
__global__ void conv3d_s1p0k4_tanh(const float* __restrict__ x, const float* __restrict__ w,
                                   const float* __restrict__ bias, float* __restrict__ y,
                                   int Cin, int Cout, int Din, int Dout)
{
    int total = Cout * Dout * Dout * Dout;
    int idx = blockIdx.x * blockDim.x + threadIdx.x;
    if (idx >= total) return;
    int ow = idx % Dout; int t = idx / Dout;
    int oh = t % Dout; t /= Dout;
    int od = t % Dout; int co = t / Dout;

    float sum = bias[co];
    const long dsz = (long)Din * Din * Din;
    const float* wb = w + (long)co * Cin * 64;
    for (int ci = 0; ci < Cin; ++ci) {
        const float* xc = x + ci * dsz;
        const float* wc = wb + ci * 64;
        #pragma unroll
        for (int kd = 0; kd < 4; ++kd) {
            #pragma unroll
            for (int kh = 0; kh < 4; ++kh) {
                const float* xr = xc + ((long)(od + kd) * Din + (oh + kh)) * Din + ow;
                const float* wr = wc + kd * 16 + kh * 4;
                #pragma unroll
                for (int kw = 0; kw < 4; ++kw)
                    sum = fmaf(xr[kw], wr[kw], sum);
            }
        }
    }
    y[idx] = tanhf(sum);
}

extern "C" void kernel_launch(void* const* d_in, const int* in_sizes, int n_in,
                              void* d_out, int out_size, void* d_ws, size_t ws_size,
                              hipStream_t stream)
{
    const float* x       = (const float*)d_in[0];
    const float* enc_w1  = (const float*)d_in[1];
    const float* enc_b1  = (const float*)d_in[2];
    const float* enc_w2  = (const float*)d_in[3];
    const float* enc_b2  = (const float*)d_in[4];
    const float* enc_w3  = (const float*)d_in[5];
    const float* enc_b3  = (const float*)d_in[6];
    const float* enc_w4  = (const float*)d_in[7];
    const float* enc_b4  = (const float*)d_in[8];
    const float* codebook= (const float*)d_in[9];
    const float* dec_w1  = (const float*)d_in[10];
    const float* dec_b1  = (const float*)d_in[11];
    const float* dec_w2  = (const float*)d_in[12];
    const float* dec_b2  = (const float*)d_in[13];
    const float* dec_w3  = (const float*)d_in[14];
    const float* dec_b3  = (const float*)d_in[15];
    const float* dec_w4  = (const float*)d_in[16];
    const float* dec_b4  = (const float*)d_in[17];

    float* out = (float*)d_out;
    float* idx_out = out + 2 * 3 * 61 * 61 * 61;  // 1361886

    // Workspace layout (floats)
    float* ws = (float*)d_ws;
    float* h1   = ws;                       // 2*64*32^3  = 4194304
    float* h2   = h1 + 4194304;             // 2*128*16^3 = 1048576
    float* h3   = h2 + 1048576;             // 2*256*8^3  = 262144
    float* lat  = h3 + 262144;              // 2*256*512  = 262144
    float* q    = lat + 262144;             // 2*256*512  = 262144
    float* cn   = q + 262144;               // 1024
    float* d1   = cn + 1024;                // 256*16^3   = 1048576 (per batch)
    float* d2   = d1 + 1048576;             // 128*32^3   = 4194304 (per batch)
    float* d3   = d2 + 4194304;             // 64*64^3    = 16777216 (per batch)
    // total ~28.05M floats ~112 MB

    dim3 blk(256);
    auto nblk = [](int n) { return dim3((unsigned)((n + 255) / 256)); };

    // ---- encoder ----
    conv3d_s2p1k4<<<nblk(2 * 64 * 32768), blk, 0, stream>>>(x, enc_w1, enc_b1, h1,
                                                            2, 3, 64, 64, 32, 1);
    conv3d_s2p1k4<<<nblk(2 * 128 * 4096), blk, 0, stream>>>(h1, enc_w2, enc_b2, h2,
                                                            2, 64, 128, 32, 16, 1);
    conv3d_s2p1k4<<<nblk(2 * 256 * 512), blk, 0, stream>>>(h2, enc_w3, enc_b3, h3,
                                                           2, 128, 256, 16, 8, 1);
    conv1x1<<<nblk(2 * 256 * 512), blk, 0, stream>>>(h3, enc_w4, enc_b4, lat,
                                                     2, 256, 256, 512);

    // ---- vector quantization ----
    codenorm_kernel<<<dim3(1024), dim3(64), 0, stream>>>(codebook, cn);
    vq_kernel<<<dim3(1024), dim3(256), 0, stream>>>(lat, codebook, cn, q, idx_out);

    // ---- decoder (per batch to keep workspace small) ----
    for (int b = 0; b < 2; ++b) {
        const float* qb = q + (long)b * 131072;
        float* outb = out + (long)b * 3 * 226981;
        convt3d_s2p1k4<<<nblk(256 * 4096), blk, 0, stream>>>(qb, dec_w1, dec_b1, d1,
                                                             256, 256, 8, 16, 1);
        convt3d_s2p1k4<<<nblk(128 * 32768), blk, 0, stream>>>(d1, dec_w2, dec_b2, d2,
                                                              256, 128, 16, 32, 1);
        convt3d_s2p1k4<<<nblk(64 * 262144), blk, 0, stream>>>(d2, dec_w3, dec_b3, d3,
                                                              128, 64, 32, 64, 1);
        conv3d_s1p0k4_tanh<<<nblk(3 * 226981), blk, 0, stream>>>(d3, dec_w4, dec_b4, outb,
                                                                 64, 3, 64, 61);
    }
}

// Round 2
// 5518.927 us; speedup vs baseline: 4.5167x; 4.5167x over previous
//
#include <hip/hip_runtime.h>
#include <cfloat>
#include <cmath>

// ---------------------------------------------------------------------------
// Round 1: register-tiled fp32 conv kernels.
// All activations stored zero-padded (+1 halo each side) so hot loops have
// ZERO bounds checks. co is wave-uniform (from blockIdx) so weight loads are
// scalar (s_load) — VALU issues almost only FMAs.
// ---------------------------------------------------------------------------

// Pad input: xp (BC, PD^3) from x (BC, D^3), halo 1 zeroed. PD = D+2.
__global__ __launch_bounds__(256) void pad_input(const float* __restrict__ x,
                                                 float* __restrict__ xp,
                                                 int BC, int D)
{
    int PD = D + 2;
    long total = (long)BC * PD * PD * PD;
    long idx = (long)blockIdx.x * blockDim.x + threadIdx.x;
    if (idx >= total) return;
    int px = (int)(idx % PD); long t = idx / PD;
    int py = (int)(t % PD); t /= PD;
    int pz = (int)(t % PD); int c = (int)(t / PD);
    int ix = px - 1, iy = py - 1, iz = pz - 1;
    float v = 0.0f;
    if ((unsigned)ix < (unsigned)D && (unsigned)iy < (unsigned)D && (unsigned)iz < (unsigned)D)
        v = x[(((long)c * D + iz) * D + iy) * D + ix];
    xp[idx] = v;
}

// Zero the halo cells of a (C, PD^3) padded buffer (interior untouched).
__global__ __launch_bounds__(256) void zero_halo(float* __restrict__ p, int C, int PD)
{
    long total = (long)C * PD * PD * PD;
    long idx = (long)blockIdx.x * blockDim.x + threadIdx.x;
    if (idx >= total) return;
    int px = (int)(idx % PD); long t = idx / PD;
    int py = (int)(t % PD); t /= PD;
    int pz = (int)(t % PD);
    if (px == 0 || px == PD - 1 || py == 0 || py == PD - 1 || pz == 0 || pz == PD - 1)
        p[idx] = 0.0f;
}

// ---------------------------------------------------------------------------
// Strided conv k=4 s=2 p=1 (+ReLU), output tile 2^3 per thread.
// xp: (B, Cin, (Din+2)^3) padded. w: (Cout, Cin, 64). y: (B, Cout, (Dout+2*po)^3).
// Contribution rule: x at region idx j contributes to output o with tap
// k = j - 2*o (valid 0..3). grid.x = B * Cout * chunks, block = 256.
// ---------------------------------------------------------------------------
__global__ __launch_bounds__(256)
void conv_s2_t2(const float* __restrict__ xp, const float* __restrict__ w,
                const float* __restrict__ bias, float* __restrict__ y,
                int B, int Cin, int Cout, int Din, int Dout,
                int chunks, int po, int relu)
{
    const int T = Dout >> 1;
    const int T3 = T * T * T;
    const int chunk = blockIdx.x % chunks;
    const int co = (blockIdx.x / chunks) % Cout;      // wave-uniform
    const int b  = blockIdx.x / (chunks * Cout);
    const int tile = chunk * blockDim.x + threadIdx.x;
    if (tile >= T3) return;
    const int tx = tile % T, ty = (tile / T) % T, tz = tile / (T * T);
    const int PD = Din + 2;
    // padded input base for this tile: i_padded = 4*t + j, j in [0,6)
    const int ibz = 4 * tz, iby = 4 * ty, ibx = 4 * tx;
    const long chstride = (long)PD * PD * PD;
    const float* xb = xp + (long)b * Cin * chstride;
    const float* wb = w + (long)co * Cin * 64;

    const float bv = bias[co];
    float acc[2][2][2];
    #pragma unroll
    for (int a = 0; a < 2; ++a)
        #pragma unroll
        for (int c = 0; c < 2; ++c)
            #pragma unroll
            for (int d = 0; d < 2; ++d) acc[a][c][d] = bv;

    for (int ci = 0; ci < Cin; ++ci) {
        const float* wr = wb + ci * 64;               // uniform -> s_load
        const float* xc = xb + ci * chstride;
        #pragma unroll
        for (int jz = 0; jz < 6; ++jz) {
            #pragma unroll
            for (int jy = 0; jy < 6; ++jy) {
                const float* row = xc + ((long)(ibz + jz) * PD + (iby + jy)) * PD + ibx;
                #pragma unroll
                for (int jx = 0; jx < 6; ++jx) {
                    const float xv = row[jx];
                    #pragma unroll
                    for (int oz = 0; oz < 2; ++oz) {
                        const int kz = jz - 2 * oz;
                        if (kz < 0 || kz > 3) continue;
                        #pragma unroll
                        for (int oy = 0; oy < 2; ++oy) {
                            const int ky = jy - 2 * oy;
                            if (ky < 0 || ky > 3) continue;
                            #pragma unroll
                            for (int ox = 0; ox < 2; ++ox) {
                                const int kx = jx - 2 * ox;
                                if (kx < 0 || kx > 3) continue;
                                acc[oz][oy][ox] = fmaf(xv, wr[(kz * 4 + ky) * 4 + kx],
                                                       acc[oz][oy][ox]);
                            }
                        }
                    }
                }
            }
        }
    }

    const int OPD = Dout + 2 * po;
    const int obz = 2 * tz + po, oby = 2 * ty + po, obx = 2 * tx + po;
    float* yb = y + (long)(b * Cout + co) * OPD * OPD * OPD;
    #pragma unroll
    for (int oz = 0; oz < 2; ++oz)
        #pragma unroll
        for (int oy = 0; oy < 2; ++oy)
            #pragma unroll
            for (int ox = 0; ox < 2; ++ox) {
                float v = acc[oz][oy][ox];
                if (relu) v = fmaxf(v, 0.0f);
                yb[((long)(obz + oz) * OPD + (oby + oy)) * OPD + (obx + ox)] = v;
            }
}

// ---------------------------------------------------------------------------
// ConvTranspose3d k=4 s=2 p=1 (+ReLU), output tile O^3 per thread, single batch.
// xp: (Cin, (Din+2)^3) padded. w: (Cin, Cout, 64). y: (Cout, (Dout+2)^3) padded.
// Scatter rule: x[j] -> out[2j+q] with tap kd=q+1; in tile coords
// oz = 2*jz - 3 + qz (qz = kd). grid.x = Cout * chunks.
// ---------------------------------------------------------------------------
template <int O>
__global__ __launch_bounds__(256)
void convt_tile(const float* __restrict__ xp, const float* __restrict__ w,
                const float* __restrict__ bias, float* __restrict__ y,
                int Cin, int Cout, int Din, int Dout, int chunks)
{
    constexpr int IC = O / 2 + 2;
    const int T = Dout / O;
    const int T3 = T * T * T;
    const int chunk = blockIdx.x % chunks;
    const int co = (blockIdx.x / chunks) % Cout;      // wave-uniform
    const int tile = chunk * blockDim.x + threadIdx.x;
    if (tile >= T3) return;
    const int tx = tile % T, ty = (tile / T) % T, tz = tile / (T * T);
    const int PD = Din + 2;
    // padded input base: j_padded = t*(O/2) + j, j in [0,IC)
    const int ibz = tz * (O / 2), iby = ty * (O / 2), ibx = tx * (O / 2);
    const long chstride = (long)PD * PD * PD;

    const float bv = bias[co];
    float acc[O][O][O];
    #pragma unroll
    for (int a = 0; a < O; ++a)
        #pragma unroll
        for (int c = 0; c < O; ++c)
            #pragma unroll
            for (int d = 0; d < O; ++d) acc[a][c][d] = bv;

    for (int ci = 0; ci < Cin; ++ci) {
        const float* wr = w + ((long)ci * Cout + co) * 64;   // uniform -> s_load
        const float* xc = xp + ci * chstride;
        #pragma unroll
        for (int jz = 0; jz < IC; ++jz) {
            #pragma unroll
            for (int jy = 0; jy < IC; ++jy) {
                const float* row = xc + ((long)(ibz + jz) * PD + (iby + jy)) * PD + ibx;
                #pragma unroll
                for (int jx = 0; jx < IC; ++jx) {
                    const float xv = row[jx];
                    #pragma unroll
                    for (int qz = 0; qz < 4; ++qz) {
                        const int oz = 2 * jz - 3 + qz;
                        if (oz < 0 || oz >= O) continue;
                        #pragma unroll
                        for (int qy = 0; qy < 4; ++qy) {
                            const int oy = 2 * jy - 3 + qy;
                            if (oy < 0 || oy >= O) continue;
                            #pragma unroll
                            for (int qx = 0; qx < 4; ++qx) {
                                const int ox = 2 * jx - 3 + qx;
                                if (ox < 0 || ox >= O) continue;
                                acc[oz][oy][ox] = fmaf(xv, wr[(qz * 4 + qy) * 4 + qx],
                                                       acc[oz][oy][ox]);
                            }
                        }
                    }
                }
            }
        }
    }

    const int OPD = Dout + 2;
    const int obz = tz * O + 1, oby = ty * O + 1, obx = tx * O + 1;
    float* yb = y + (long)co * OPD * OPD * OPD;
    #pragma unroll
    for (int oz = 0; oz < O; ++oz)
        #pragma unroll
        for (int oy = 0; oy < O; ++oy)
            #pragma unroll
            for (int ox = 0; ox < O; ++ox) {
                float v = fmaxf(acc[oz][oy][ox], 0.0f);
                yb[((long)(obz + oz) * OPD + (oby + oy)) * OPD + (obx + ox)] = v;
            }
}

// ---------------------------------------------------------------------------
// Final conv k=4 s=1 p=0 + tanh, output tile 2^3 per thread, single batch.
// xp: (Cin, 66^3) padded. w: (Cout, Cin, 64). y: (Cout, Dout^3) unpadded, Dout=61.
// Contribution: x at j contributes to o with tap k = j - o (valid 0..3).
// ---------------------------------------------------------------------------
__global__ __launch_bounds__(256)
void conv_s1_t2_tanh(const float* __restrict__ xp, const float* __restrict__ w,
                     const float* __restrict__ bias, float* __restrict__ y,
                     int Cin, int Cout, int Din, int Dout, int chunks)
{
    const int T = (Dout + 1) >> 1;      // 31
    const int T3 = T * T * T;
    const int chunk = blockIdx.x % chunks;
    const int co = (blockIdx.x / chunks) % Cout;      // wave-uniform
    const int tile = chunk * blockDim.x + threadIdx.x;
    if (tile >= T3) return;
    const int tx = tile % T, ty = (tile / T) % T, tz = tile / (T * T);
    const int PD = Din + 2;
    // padded input base: i_padded = 2*t + j + 1, j in [0,5)
    const int ibz = 2 * tz + 1, iby = 2 * ty + 1, ibx = 2 * tx + 1;
    const long chstride = (long)PD * PD * PD;
    const float* wb = w + (long)co * Cin * 64;

    const float bv = bias[co];
    float acc[2][2][2];
    #pragma unroll
    for (int a = 0; a < 2; ++a)
        #pragma unroll
        for (int c = 0; c < 2; ++c)
            #pragma unroll
            for (int d = 0; d < 2; ++d) acc[a][c][d] = bv;

    for (int ci = 0; ci < Cin; ++ci) {
        const float* wr = wb + ci * 64;               // uniform -> s_load
        const float* xc = xp + ci * chstride;
        #pragma unroll
        for (int jz = 0; jz < 5; ++jz) {
            #pragma unroll
            for (int jy = 0; jy < 5; ++jy) {
                const float* row = xc + ((long)(ibz + jz) * PD + (iby + jy)) * PD + ibx;
                #pragma unroll
                for (int jx = 0; jx < 5; ++jx) {
                    const float xv = row[jx];
                    #pragma unroll
                    for (int oz = 0; oz < 2; ++oz) {
                        const int kz = jz - oz;
                        if (kz < 0 || kz > 3) continue;
                        #pragma unroll
                        for (int oy = 0; oy < 2; ++oy) {
                            const int ky = jy - oy;
                            if (ky < 0 || ky > 3) continue;
                            #pragma unroll
                            for (int ox = 0; ox < 2; ++ox) {
                                const int kx = jx - ox;
                                if (kx < 0 || kx > 3) continue;
                                acc[oz][oy][ox] = fmaf(xv, wr[(kz * 4 + ky) * 4 + kx],
                                                       acc[oz][oy][ox]);
                            }
                        }
                    }
                }
            }
        }
    }

    #pragma unroll
    for (int oz = 0; oz < 2; ++oz) {
        const int od = 2 * tz + oz; if (od >= Dout) continue;
        #pragma unroll
        for (int oy = 0; oy < 2; ++oy) {
            const int oh = 2 * ty + oy; if (oh >= Dout) continue;
            #pragma unroll
            for (int ox = 0; ox < 2; ++ox) {
                const int ow = 2 * tx + ox; if (ow >= Dout) continue;
                y[((long)(co * Dout + od) * Dout + oh) * Dout + ow] = tanhf(acc[oz][oy][ox]);
            }
        }
    }
}

// 1x1 conv: x:(N,Cin,Sp) w:(Cout,Cin) -> y:(N,Cout,Sp).
__global__ __launch_bounds__(256)
void conv1x1(const float* __restrict__ x, const float* __restrict__ w,
             const float* __restrict__ bias, float* __restrict__ y,
             int N, int Cin, int Cout, int Sp)
{
    int total = N * Cout * Sp;
    int idx = blockIdx.x * blockDim.x + threadIdx.x;
    if (idx >= total) return;
    int s = idx % Sp;
    int co = (idx / Sp) % Cout;
    int n = idx / (Sp * Cout);
    float sum = bias[co];
    const float* xb = x + (long)n * Cin * Sp + s;
    const float* wb = w + (long)co * Cin;
    for (int ci = 0; ci < Cin; ++ci)
        sum = fmaf(xb[(long)ci * Sp], wb[ci], sum);
    y[idx] = sum;
}

// Codebook row squared norms. grid = K blocks of 64 lanes.
__global__ void codenorm_kernel(const float* __restrict__ cb, float* __restrict__ norms)
{
    int k = blockIdx.x;
    int lane = threadIdx.x;
    float s = 0.0f;
    const float* row = cb + (long)k * 256;
    for (int d = lane; d < 256; d += 64) { float v = row[d]; s = fmaf(v, v, s); }
    for (int off = 32; off > 0; off >>= 1) s += __shfl_down(s, off);
    if (lane == 0) norms[k] = s;
}

// VQ: one block (256 thr) per latent row. Writes q into PADDED (B,256,10^3)
// layout (halo pre-zeroed) and idx as float.
__global__ __launch_bounds__(256)
void vq_kernel(const float* __restrict__ lat, const float* __restrict__ cb,
               const float* __restrict__ norms, float* __restrict__ q,
               float* __restrict__ idx_out)
{
    __shared__ float row[256];
    __shared__ float s_best[256];
    __shared__ int   s_bidx[256];
    int r = blockIdx.x;       // r = b*512 + n
    int t = threadIdx.x;
    row[t] = lat[(long)r * 256 + t];
    __syncthreads();

    float latn = 0.0f;
    for (int d = 0; d < 256; ++d) latn = fmaf(row[d], row[d], latn);

    float best = FLT_MAX;
    int bidx = 0x7fffffff;
    for (int j = 0; j < 4; ++j) {
        int k = t + 256 * j;
        const float* cr = cb + (long)k * 256;
        float dot = 0.0f;
        for (int d = 0; d < 256; ++d) dot = fmaf(row[d], cr[d], dot);
        float sc = latn - 2.0f * dot + norms[k];
        if (sc < best || (sc == best && k < bidx)) { best = sc; bidx = k; }
    }
    s_best[t] = best; s_bidx[t] = bidx;
    __syncthreads();
    for (int off = 128; off > 0; off >>= 1) {
        if (t < off) {
            float o = s_best[t + off]; int oi = s_bidx[t + off];
            if (o < s_best[t] || (o == s_best[t] && oi < s_bidx[t])) {
                s_best[t] = o; s_bidx[t] = oi;
            }
        }
        __syncthreads();
    }
    int bk = s_bidx[0];
    int b = r >> 9, n = r & 511;
    int zz = n >> 6, yy = (n >> 3) & 7, xx = n & 7;
    q[(long)(b * 256 + t) * 1000 + ((long)(zz + 1) * 10 + (yy + 1)) * 10 + (xx + 1)]
        = cb[(long)bk * 256 + t];
    if (t == 0) idx_out[r] = (float)bk;
}

extern "C" void kernel_launch(void* const* d_in, const int* in_sizes, int n_in,
                              void* d_out, int out_size, void* d_ws, size_t ws_size,
                              hipStream_t stream)
{
    const float* x        = (const float*)d_in[0];
    const float* enc_w1   = (const float*)d_in[1];
    const float* enc_b1   = (const float*)d_in[2];
    const float* enc_w2   = (const float*)d_in[3];
    const float* enc_b2   = (const float*)d_in[4];
    const float* enc_w3   = (const float*)d_in[5];
    const float* enc_b3   = (const float*)d_in[6];
    const float* enc_w4   = (const float*)d_in[7];
    const float* enc_b4   = (const float*)d_in[8];
    const float* codebook = (const float*)d_in[9];
    const float* dec_w1   = (const float*)d_in[10];
    const float* dec_b1   = (const float*)d_in[11];
    const float* dec_w2   = (const float*)d_in[12];
    const float* dec_b2   = (const float*)d_in[13];
    const float* dec_w3   = (const float*)d_in[14];
    const float* dec_b3   = (const float*)d_in[15];
    const float* dec_w4   = (const float*)d_in[16];
    const float* dec_b4   = (const float*)d_in[17];

    float* out = (float*)d_out;
    float* idx_out = out + 2L * 3 * 61 * 61 * 61;   // 1,361,886

    // ---- workspace layout (floats); liveness-checked overlapping arena ----
    float* ws  = (float*)d_ws;
    float* qp  = ws;                     //   512,000  (2,256,10^3) padded q
    float* cn  = ws + 512000;            //     1,024
    float* A   = ws + 513024;            // arena
    float* xp  = A;                      // 1,724,976  (2,3,66^3)
    float* h1p = A + 1724976;            // 5,030,912  (2,64,34^3)
    float* h2p = A;                      // 1,492,992  (2,128,18^3)   [xp dead]
    float* h3  = A + 1492992;            //   262,144  (2,256,8^3) unpadded [h1p dead]
    float* lat = A + 1755136;            //   262,144  (2,512,256 rows)
    float* d1p = A;                      // 1,492,992  (256,18^3) per batch [enc dead]
    float* d2p = A + 1492992;            // 5,030,912  (128,34^3) per batch
    float* d3p = A + 6523904;            // 18,399,744 (64,66^3) per batch
    // total: 513,024 + 24,923,648 = 25,436,672 floats = 101.7 MB

    dim3 blk(256);
    auto nblk = [](long n) { return dim3((unsigned)((n + 255) / 256)); };

    // ---- pad input ----
    pad_input<<<nblk(6L * 66 * 66 * 66), blk, 0, stream>>>(x, xp, 6, 64);

    // ---- encoder ----
    zero_halo<<<nblk(128L * 34 * 34 * 34), blk, 0, stream>>>(h1p, 128, 34);
    // enc1: Cin=3 Cout=64 Din=64 Dout=32: T3=4096, chunks=16, grid=2*64*16
    conv_s2_t2<<<dim3(2 * 64 * 16), blk, 0, stream>>>(xp, enc_w1, enc_b1, h1p,
                                                      2, 3, 64, 64, 32, 16, 1, 1);
    zero_halo<<<nblk(256L * 18 * 18 * 18), blk, 0, stream>>>(h2p, 256, 18);
    // enc2: Cin=64 Cout=128 Din=32 Dout=16: T3=512, chunks=2, grid=2*128*2
    conv_s2_t2<<<dim3(2 * 128 * 2), blk, 0, stream>>>(h1p, enc_w2, enc_b2, h2p,
                                                      2, 64, 128, 32, 16, 2, 1, 1);
    // enc3: Cin=128 Cout=256 Din=16 Dout=8: T3=64, chunks=1, grid=2*256; unpadded out
    conv_s2_t2<<<dim3(2 * 256), blk, 0, stream>>>(h2p, enc_w3, enc_b3, h3,
                                                  2, 128, 256, 16, 8, 1, 0, 1);
    conv1x1<<<nblk(2L * 256 * 512), blk, 0, stream>>>(h3, enc_w4, enc_b4, lat,
                                                      2, 256, 256, 512);

    // ---- vector quantization ----
    codenorm_kernel<<<dim3(1024), dim3(64), 0, stream>>>(codebook, cn);
    zero_halo<<<nblk(512L * 10 * 10 * 10), blk, 0, stream>>>(qp, 512, 10);
    vq_kernel<<<dim3(1024), blk, 0, stream>>>(lat, codebook, cn, qp, idx_out);

    // ---- decoder halos (zeroed once; interiors overwritten per batch) ----
    zero_halo<<<nblk(256L * 18 * 18 * 18), blk, 0, stream>>>(d1p, 256, 18);
    zero_halo<<<nblk(128L * 34 * 34 * 34), blk, 0, stream>>>(d2p, 128, 34);
    zero_halo<<<nblk(64L * 66 * 66 * 66), blk, 0, stream>>>(d3p, 64, 66);

    // ---- decoder (per batch; arenas reused) ----
    for (int b = 0; b < 2; ++b) {
        const float* qb = qp + (long)b * 256 * 1000;
        float* outb = out + (long)b * 3 * 226981;
        // dec1: Cin=256 Cout=256 Din=8 Dout=16, O=2: T3=512, chunks=2, grid=256*2
        convt_tile<2><<<dim3(256 * 2), blk, 0, stream>>>(qb, dec_w1, dec_b1, d1p,
                                                         256, 256, 8, 16, 2);
        // dec2: Cin=256 Cout=128 Din=16 Dout=32, O=4: T3=512, chunks=2, grid=128*2
        convt_tile<4><<<dim3(128 * 2), blk, 0, stream>>>(d1p, dec_w2, dec_b2, d2p,
                                                         256, 128, 16, 32, 2);
        // dec3: Cin=128 Cout=64 Din=32 Dout=64, O=4: T3=4096, chunks=16, grid=64*16
        convt_tile<4><<<dim3(64 * 16), blk, 0, stream>>>(d2p, dec_w3, dec_b3, d3p,
                                                         128, 64, 32, 64, 16);
        // dec4: Cin=64 Cout=3 Din=64 Dout=61: T3=29791, chunks=117, grid=3*117
        conv_s1_t2_tanh<<<dim3(3 * 117), blk, 0, stream>>>(d3p, dec_w4, dec_b4, outb,
                                                           64, 3, 64, 61, 117);
    }
}

// Round 3
// 3228.379 us; speedup vs baseline: 7.7214x; 1.7095x over previous
//
#include <hip/hip_runtime.h>
#include <cfloat>
#include <cmath>

// ---------------------------------------------------------------------------
// Round 2: decoder ConvTranspose3d -> bf16 MFMA implicit GEMM (8 parity
// classes, per-lane 2x2x2-cube B gather, pre-gathered A weights).
// Encoder + VQ stay fp32 (exact argmin for the index output).
// ---------------------------------------------------------------------------

using f32x4  = __attribute__((ext_vector_type(4))) float;
using bf16x8 = __attribute__((ext_vector_type(8))) short;

__device__ __forceinline__ unsigned short f32_to_bf16(float f) {
    unsigned int u = __float_as_uint(f);
    u += 0x7fffu + ((u >> 16) & 1u);          // round-to-nearest-even
    return (unsigned short)(u >> 16);
}
__device__ __forceinline__ void store_act(float* p, float v) { *p = v; }
__device__ __forceinline__ void store_act(unsigned short* p, float v) { *p = f32_to_bf16(v); }

// ---------------- padding / halo utilities ----------------
__global__ __launch_bounds__(256) void pad_input(const float* __restrict__ x,
                                                 float* __restrict__ xp, int BC, int D)
{
    int PD = D + 2;
    long total = (long)BC * PD * PD * PD;
    long idx = (long)blockIdx.x * blockDim.x + threadIdx.x;
    if (idx >= total) return;
    int px = (int)(idx % PD); long t = idx / PD;
    int py = (int)(t % PD); t /= PD;
    int pz = (int)(t % PD); int c = (int)(t / PD);
    int ix = px - 1, iy = py - 1, iz = pz - 1;
    float v = 0.0f;
    if ((unsigned)ix < (unsigned)D && (unsigned)iy < (unsigned)D && (unsigned)iz < (unsigned)D)
        v = x[(((long)c * D + iz) * D + iy) * D + ix];
    xp[idx] = v;
}

template <typename T>
__global__ __launch_bounds__(256) void zero_halo_t(T* __restrict__ p, int C, int PD)
{
    long total = (long)C * PD * PD * PD;
    long idx = (long)blockIdx.x * blockDim.x + threadIdx.x;
    if (idx >= total) return;
    int px = (int)(idx % PD); long t = idx / PD;
    int py = (int)(t % PD); t /= PD;
    int pz = (int)(t % PD);
    if (px == 0 || px == PD - 1 || py == 0 || py == PD - 1 || pz == 0 || pz == PD - 1)
        p[idx] = (T)0;
}

// ---------------- encoder (fp32, register-tiled; unchanged from R1) --------
__global__ __launch_bounds__(256)
void conv_s2_t2(const float* __restrict__ xp, const float* __restrict__ w,
                const float* __restrict__ bias, float* __restrict__ y,
                int B, int Cin, int Cout, int Din, int Dout,
                int chunks, int po, int relu)
{
    const int T = Dout >> 1;
    const int T3 = T * T * T;
    const int chunk = blockIdx.x % chunks;
    const int co = (blockIdx.x / chunks) % Cout;
    const int b  = blockIdx.x / (chunks * Cout);
    const int tile = chunk * blockDim.x + threadIdx.x;
    if (tile >= T3) return;
    const int tx = tile % T, ty = (tile / T) % T, tz = tile / (T * T);
    const int PD = Din + 2;
    const int ibz = 4 * tz, iby = 4 * ty, ibx = 4 * tx;
    const long chstride = (long)PD * PD * PD;
    const float* xb = xp + (long)b * Cin * chstride;
    const float* wb = w + (long)co * Cin * 64;

    const float bv = bias[co];
    float acc[2][2][2];
    #pragma unroll
    for (int a = 0; a < 2; ++a)
        #pragma unroll
        for (int c = 0; c < 2; ++c)
            #pragma unroll
            for (int d = 0; d < 2; ++d) acc[a][c][d] = bv;

    for (int ci = 0; ci < Cin; ++ci) {
        const float* wr = wb + ci * 64;
        const float* xc = xb + ci * chstride;
        #pragma unroll
        for (int jz = 0; jz < 6; ++jz) {
            #pragma unroll
            for (int jy = 0; jy < 6; ++jy) {
                const float* row = xc + ((long)(ibz + jz) * PD + (iby + jy)) * PD + ibx;
                #pragma unroll
                for (int jx = 0; jx < 6; ++jx) {
                    const float xv = row[jx];
                    #pragma unroll
                    for (int oz = 0; oz < 2; ++oz) {
                        const int kz = jz - 2 * oz;
                        if (kz < 0 || kz > 3) continue;
                        #pragma unroll
                        for (int oy = 0; oy < 2; ++oy) {
                            const int ky = jy - 2 * oy;
                            if (ky < 0 || ky > 3) continue;
                            #pragma unroll
                            for (int ox = 0; ox < 2; ++ox) {
                                const int kx = jx - 2 * ox;
                                if (kx < 0 || kx > 3) continue;
                                acc[oz][oy][ox] = fmaf(xv, wr[(kz * 4 + ky) * 4 + kx],
                                                       acc[oz][oy][ox]);
                            }
                        }
                    }
                }
            }
        }
    }

    const int OPD = Dout + 2 * po;
    const int obz = 2 * tz + po, oby = 2 * ty + po, obx = 2 * tx + po;
    float* yb = y + (long)(b * Cout + co) * OPD * OPD * OPD;
    #pragma unroll
    for (int oz = 0; oz < 2; ++oz)
        #pragma unroll
        for (int oy = 0; oy < 2; ++oy)
            #pragma unroll
            for (int ox = 0; ox < 2; ++ox) {
                float v = acc[oz][oy][ox];
                if (relu) v = fmaxf(v, 0.0f);
                yb[((long)(obz + oz) * OPD + (oby + oy)) * OPD + (obx + ox)] = v;
            }
}

__global__ __launch_bounds__(256)
void conv1x1(const float* __restrict__ x, const float* __restrict__ w,
             const float* __restrict__ bias, float* __restrict__ y,
             int N, int Cin, int Cout, int Sp)
{
    int total = N * Cout * Sp;
    int idx = blockIdx.x * blockDim.x + threadIdx.x;
    if (idx >= total) return;
    int s = idx % Sp;
    int co = (idx / Sp) % Cout;
    int n = idx / (Sp * Cout);
    float sum = bias[co];
    const float* xb = x + (long)n * Cin * Sp + s;
    const float* wb = w + (long)co * Cin;
    for (int ci = 0; ci < Cin; ++ci)
        sum = fmaf(xb[(long)ci * Sp], wb[ci], sum);
    y[idx] = sum;
}

// ---------------- VQ (fp32 exact) ----------------
__global__ void codenorm_kernel(const float* __restrict__ cb, float* __restrict__ norms)
{
    int k = blockIdx.x;
    int lane = threadIdx.x;
    float s = 0.0f;
    const float* row = cb + (long)k * 256;
    for (int d = lane; d < 256; d += 64) { float v = row[d]; s = fmaf(v, v, s); }
    for (int off = 32; off > 0; off >>= 1) s += __shfl_down(s, off);
    if (lane == 0) norms[k] = s;
}

// q written as bf16 into padded (B,256,10^3); idx as float.
__global__ __launch_bounds__(256)
void vq_kernel(const float* __restrict__ lat, const float* __restrict__ cb,
               const float* __restrict__ norms, unsigned short* __restrict__ q,
               float* __restrict__ idx_out)
{
    __shared__ float row[256];
    __shared__ float s_best[256];
    __shared__ int   s_bidx[256];
    int r = blockIdx.x;
    int t = threadIdx.x;
    row[t] = lat[(long)r * 256 + t];
    __syncthreads();

    float latn = 0.0f;
    for (int d = 0; d < 256; ++d) latn = fmaf(row[d], row[d], latn);

    float best = FLT_MAX;
    int bidx = 0x7fffffff;
    for (int j = 0; j < 4; ++j) {
        int k = t + 256 * j;
        const float* cr = cb + (long)k * 256;
        float dot = 0.0f;
        for (int d = 0; d < 256; ++d) dot = fmaf(row[d], cr[d], dot);
        float sc = latn - 2.0f * dot + norms[k];
        if (sc < best || (sc == best && k < bidx)) { best = sc; bidx = k; }
    }
    s_best[t] = best; s_bidx[t] = bidx;
    __syncthreads();
    for (int off = 128; off > 0; off >>= 1) {
        if (t < off) {
            float o = s_best[t + off]; int oi = s_bidx[t + off];
            if (o < s_best[t] || (o == s_best[t] && oi < s_bidx[t])) {
                s_best[t] = o; s_bidx[t] = oi;
            }
        }
        __syncthreads();
    }
    int bk = s_bidx[0];
    int b = r >> 9, n = r & 511;
    int zz = n >> 6, yy = (n >> 3) & 7, xx = n & 7;
    q[(long)(b * 256 + t) * 1000 + ((long)(zz + 1) * 10 + (yy + 1)) * 10 + (xx + 1)]
        = f32_to_bf16(cb[(long)bk * 256 + t]);
    if (t == 0) idx_out[r] = (float)bk;
}

// ---------------- decoder: MFMA implicit-GEMM ConvTranspose ----------------
// A-weight pre-gather: Ap[p][co][k], k = ci*8 + a, a = az*4+ay*2+ax,
// tap (kd,kh,kw) = (1-p?)+2a per dim. bf16 stored as short.
__global__ __launch_bounds__(256)
void prep_convt_w(const float* __restrict__ w, short* __restrict__ Ap,
                  int Cin, int Cout)
{
    const int K = Cin * 8;
    long total = 8L * Cout * K;
    long idx = (long)blockIdx.x * blockDim.x + threadIdx.x;
    if (idx >= total) return;
    int k = (int)(idx % K);
    int co = (int)((idx / K) % Cout);
    int p = (int)(idx / ((long)K * Cout));
    int ci = k >> 3, a = k & 7;
    int az = (a >> 2) & 1, ay = (a >> 1) & 1, ax = a & 1;
    int pz = p >> 2, py = (p >> 1) & 1, px = p & 1;
    int kd = (1 - pz) + 2 * az, kh = (1 - py) + 2 * ay, kw = (1 - px) + 2 * ax;
    float v = w[((long)ci * Cout + co) * 64 + kd * 16 + kh * 4 + kw];
    Ap[idx] = (short)f32_to_bf16(v);
}

// ConvT s2 k4 p1 per parity class as GEMM M=Cout, N=DIN^3, K=Cin*8.
// Xp: (Cin, (DIN+2)^3) bf16. Y: (Cout, (2*DIN+2)^3) padded, ReLU.
// Block: 4 waves, tile M=64 x N=64 (N-tile = 4^3 cube of m-positions).
// grid.x = 8 * NT * (Cout/64).
template <int DIN, typename OutT>
__global__ __launch_bounds__(256)
void convt_mfma(const unsigned short* __restrict__ Xp, const short* __restrict__ Ap,
                const float* __restrict__ bias, OutT* __restrict__ Y,
                int Cin, int Cout)
{
    constexpr int PD = DIN + 2;
    constexpr int PD3 = PD * PD * PD;
    constexpr int T = DIN >> 2;
    constexpr int NT = T * T * T;
    constexpr int OPD = 2 * DIN + 2;
    const int K = Cin * 8;
    const int MG = Cout >> 6;

    int bx = blockIdx.x;
    const int mg = bx % MG; bx /= MG;
    const int nt = bx % NT; bx /= NT;
    const int p = bx;                       // parity class 0..7
    const int pz = p >> 2, py = (p >> 1) & 1, px = p & 1;

    const int lane = threadIdx.x & 63, wave = threadIdx.x >> 6;
    const int n16 = lane & 15, quad = lane >> 4;

    const int tx = nt % T, ty = (nt / T) % T, tz = nt / (T * T);
    const int mz = tz * 4 + wave, my = ty * 4 + (n16 >> 2), mx = tx * 4 + (n16 & 3);
    // 2x2x2 gather cube base (padded coords): m + p
    const int sp = ((mz + pz) * PD + (my + py)) * PD + (mx + px);

    const unsigned short* xq = Xp + (long)quad * PD3 + sp;

    const int cobase = mg * 64;
    const short* ap0 = Ap + ((long)p * Cout + cobase + n16) * K + quad * 8;

    f32x4 acc[4];
    #pragma unroll
    for (int cb = 0; cb < 4; ++cb) {
        const float* bp = bias + cobase + cb * 16 + quad * 4;
        acc[cb][0] = bp[0]; acc[cb][1] = bp[1]; acc[cb][2] = bp[2]; acc[cb][3] = bp[3];
    }

    const int nsteps = K >> 5;              // K/32, quad covers ci = s*4+quad
    for (int s = 0; s < nsteps; ++s) {
        bf16x8 bf;                          // b[j=a] = Xp[ci][cube + (1-a)]
        bf[0] = (short)xq[(PD + 1) * PD + 1];
        bf[1] = (short)xq[(PD + 1) * PD];
        bf[2] = (short)xq[PD * PD + 1];
        bf[3] = (short)xq[PD * PD];
        bf[4] = (short)xq[PD + 1];
        bf[5] = (short)xq[PD];
        bf[6] = (short)xq[1];
        bf[7] = (short)xq[0];
        #pragma unroll
        for (int cb = 0; cb < 4; ++cb) {
            bf16x8 af = *(const bf16x8*)(ap0 + (long)cb * 16 * K + s * 32);
            acc[cb] = __builtin_amdgcn_mfma_f32_16x16x32_bf16(af, bf, acc[cb], 0, 0, 0);
        }
        xq += 4 * PD3;
    }

    const int opz = 2 * mz + pz + 1, opy = 2 * my + py + 1, opx = 2 * mx + px + 1;
    const long spo = ((long)opz * OPD + opy) * OPD + opx;
    #pragma unroll
    for (int cb = 0; cb < 4; ++cb) {
        #pragma unroll
        for (int r = 0; r < 4; ++r) {
            int co = cobase + cb * 16 + quad * 4 + r;
            float v = fmaxf(acc[cb][r], 0.0f);
            store_act(Y + (long)co * OPD * OPD * OPD + spo, v);
        }
    }
}

// ---------------- final conv k4 s1 p0 + tanh (fp32) ----------------
// x: (64, 66^3) padded fp32. Tile (z,y,x) = (1,2,2). grid = 3*61*4.
__global__ __launch_bounds__(256)
void conv_dec4_tanh(const float* __restrict__ xp, const float* __restrict__ w,
                    const float* __restrict__ bias, float* __restrict__ y)
{
    constexpr int PD = 66, Dout = 61, Cin = 64;
    int bx = blockIdx.x;
    const int chunk = bx & 3; bx >>= 2;
    const int oz = bx % Dout, co = bx / Dout;
    int t = chunk * 256 + (int)threadIdx.x;
    if (t >= 31 * 31) return;
    const int tyy = t / 31, txx = t % 31;
    const int oy = 2 * tyy, ox = 2 * txx;

    const float bv = bias[co];
    float a00 = bv, a01 = bv, a10 = bv, a11 = bv;
    const float* wb = w + (long)co * Cin * 64;
    for (int ci = 0; ci < Cin; ++ci) {
        const float* wc = wb + ci * 64;
        const float* xc = xp + (long)ci * PD * PD * PD;
        #pragma unroll
        for (int jz = 0; jz < 4; ++jz) {
            const float* xz = xc + (long)(oz + 1 + jz) * PD * PD;
            #pragma unroll
            for (int jy = 0; jy < 5; ++jy) {
                const float* row = xz + (oy + 1 + jy) * PD + (ox + 1);
                float r0 = row[0], r1 = row[1], r2 = row[2], r3 = row[3], r4 = row[4];
                const float* wr = wc + jz * 16;
                if (jy < 4) {                           // oy2 = 0, ky = jy
                    const float* wk = wr + jy * 4;
                    a00 = fmaf(r0, wk[0], a00); a00 = fmaf(r1, wk[1], a00);
                    a00 = fmaf(r2, wk[2], a00); a00 = fmaf(r3, wk[3], a00);
                    a01 = fmaf(r1, wk[0], a01); a01 = fmaf(r2, wk[1], a01);
                    a01 = fmaf(r3, wk[2], a01); a01 = fmaf(r4, wk[3], a01);
                }
                if (jy >= 1) {                          // oy2 = 1, ky = jy-1
                    const float* wk = wr + (jy - 1) * 4;
                    a10 = fmaf(r0, wk[0], a10); a10 = fmaf(r1, wk[1], a10);
                    a10 = fmaf(r2, wk[2], a10); a10 = fmaf(r3, wk[3], a10);
                    a11 = fmaf(r1, wk[0], a11); a11 = fmaf(r2, wk[1], a11);
                    a11 = fmaf(r3, wk[2], a11); a11 = fmaf(r4, wk[3], a11);
                }
            }
        }
    }
    long base = ((long)co * Dout + oz) * Dout * Dout;
    y[base + (long)oy * Dout + ox] = tanhf(a00);
    if (ox + 1 < Dout) y[base + (long)oy * Dout + ox + 1] = tanhf(a01);
    if (oy + 1 < Dout) {
        y[base + (long)(oy + 1) * Dout + ox] = tanhf(a10);
        if (ox + 1 < Dout) y[base + (long)(oy + 1) * Dout + ox + 1] = tanhf(a11);
    }
}

extern "C" void kernel_launch(void* const* d_in, const int* in_sizes, int n_in,
                              void* d_out, int out_size, void* d_ws, size_t ws_size,
                              hipStream_t stream)
{
    const float* x        = (const float*)d_in[0];
    const float* enc_w1   = (const float*)d_in[1];
    const float* enc_b1   = (const float*)d_in[2];
    const float* enc_w2   = (const float*)d_in[3];
    const float* enc_b2   = (const float*)d_in[4];
    const float* enc_w3   = (const float*)d_in[5];
    const float* enc_b3   = (const float*)d_in[6];
    const float* enc_w4   = (const float*)d_in[7];
    const float* enc_b4   = (const float*)d_in[8];
    const float* codebook = (const float*)d_in[9];
    const float* dec_w1   = (const float*)d_in[10];
    const float* dec_b1   = (const float*)d_in[11];
    const float* dec_w2   = (const float*)d_in[12];
    const float* dec_b2   = (const float*)d_in[13];
    const float* dec_w3   = (const float*)d_in[14];
    const float* dec_b3   = (const float*)d_in[15];
    const float* dec_w4   = (const float*)d_in[16];
    const float* dec_b4   = (const float*)d_in[17];

    float* out = (float*)d_out;
    float* idx_out = out + 2L * 3 * 61 * 61 * 61;

    // ---- workspace (byte offsets; persistent | overlapped arena) ----
    char* wsb = (char*)d_ws;
    float*          cn  = (float*)wsb;                          //     4,096 B
    unsigned short* qp  = (unsigned short*)(wsb + 4096);        // 1,024,000 B (2,256,10^3) bf16
    short*          Ap1 = (short*)(wsb + 1028096);              // 8,388,608 B
    short*          Ap2 = (short*)(wsb + 9416704);              // 4,194,304 B
    short*          Ap3 = (short*)(wsb + 13611008);             // 1,048,576 B
    char* arena = wsb + 14659584;
    // encoder phase (fp32):
    float* xp  = (float*)arena;                 // 1,724,976 f (2,3,66^3)
    float* h1p = (float*)arena + 1724976;       // 5,030,912 f (2,64,34^3)
    float* h2p = (float*)arena;                 // 1,492,992 f (2,128,18^3)  [xp dead]
    float* h3  = (float*)arena + 1492992;       //   262,144 f (2,256,8^3)   [h1p dead]
    float* lat = (float*)arena + 1755136;       //   262,144 f
    // decoder phase (after VQ; overlaps encoder buffers):
    unsigned short* d1 = (unsigned short*)arena;                  // (256,18^3) bf16
    unsigned short* d2 = (unsigned short*)(arena + 2985984);      // (128,34^3) bf16
    float*          d3 = (float*)(arena + 13047808);              // (64,66^3) fp32
    // arena peak 86,646,784 B; total 101,306,368 B (< 112 MB proven in R0)

    dim3 blk(256);
    auto nblk = [](long n) { return dim3((unsigned)((n + 255) / 256)); };

    // ---- decoder weight pre-gather (independent; run first) ----
    prep_convt_w<<<nblk(8L * 256 * 2048), blk, 0, stream>>>(dec_w1, Ap1, 256, 256);
    prep_convt_w<<<nblk(8L * 128 * 2048), blk, 0, stream>>>(dec_w2, Ap2, 256, 128);
    prep_convt_w<<<nblk(8L * 64 * 1024), blk, 0, stream>>>(dec_w3, Ap3, 128, 64);

    // ---- encoder (fp32) ----
    pad_input<<<nblk(6L * 66 * 66 * 66), blk, 0, stream>>>(x, xp, 6, 64);
    zero_halo_t<float><<<nblk(128L * 34 * 34 * 34), blk, 0, stream>>>(h1p, 128, 34);
    conv_s2_t2<<<dim3(2 * 64 * 16), blk, 0, stream>>>(xp, enc_w1, enc_b1, h1p,
                                                      2, 3, 64, 64, 32, 16, 1, 1);
    zero_halo_t<float><<<nblk(256L * 18 * 18 * 18), blk, 0, stream>>>(h2p, 256, 18);
    conv_s2_t2<<<dim3(2 * 128 * 2), blk, 0, stream>>>(h1p, enc_w2, enc_b2, h2p,
                                                      2, 64, 128, 32, 16, 2, 1, 1);
    conv_s2_t2<<<dim3(2 * 256), blk, 0, stream>>>(h2p, enc_w3, enc_b3, h3,
                                                  2, 128, 256, 16, 8, 1, 0, 1);
    conv1x1<<<nblk(2L * 256 * 512), blk, 0, stream>>>(h3, enc_w4, enc_b4, lat,
                                                      2, 256, 256, 512);

    // ---- VQ (fp32 exact) ----
    codenorm_kernel<<<dim3(1024), dim3(64), 0, stream>>>(codebook, cn);
    zero_halo_t<unsigned short><<<nblk(512L * 10 * 10 * 10), blk, 0, stream>>>(qp, 512, 10);
    vq_kernel<<<dim3(1024), blk, 0, stream>>>(lat, codebook, cn, qp, idx_out);

    // ---- decoder halos (AFTER vq: d1/d2 overlap lat) ----
    zero_halo_t<unsigned short><<<nblk(256L * 18 * 18 * 18), blk, 0, stream>>>(d1, 256, 18);
    zero_halo_t<unsigned short><<<nblk(128L * 34 * 34 * 34), blk, 0, stream>>>(d2, 128, 34);
    zero_halo_t<float><<<nblk(64L * 66 * 66 * 66), blk, 0, stream>>>(d3, 64, 66);

    // ---- decoder (MFMA) per batch ----
    for (int b = 0; b < 2; ++b) {
        const unsigned short* qb = qp + (long)b * 256 * 1000;
        float* outb = out + (long)b * 3 * 226981;
        // dec1: Cin=256 Cout=256 Din=8:  grid = 8 par * 8 NT * 4 MG
        convt_mfma<8, unsigned short><<<dim3(8 * 8 * 4), blk, 0, stream>>>(
            qb, Ap1, dec_b1, d1, 256, 256);
        // dec2: Cin=256 Cout=128 Din=16: grid = 8 * 64 * 2
        convt_mfma<16, unsigned short><<<dim3(8 * 64 * 2), blk, 0, stream>>>(
            d1, Ap2, dec_b2, d2, 256, 128);
        // dec3: Cin=128 Cout=64 Din=32:  grid = 8 * 512 * 1 -> fp32 out for dec4
        convt_mfma<32, float><<<dim3(8 * 512), blk, 0, stream>>>(
            d2, Ap3, dec_b3, d3, 128, 64);
        // dec4 + tanh
        conv_dec4_tanh<<<dim3(3 * 61 * 4), blk, 0, stream>>>(d3, dec_w4, dec_b4, outb);
    }
}

// Round 4
// 3141.554 us; speedup vs baseline: 7.9348x; 1.0276x over previous
//
#include <hip/hip_runtime.h>
#include <cfloat>
#include <cmath>

// ---------------------------------------------------------------------------
// Round 3: fp32 encoder/dec4 rewritten as plane-staged register tiles with
// vectorized loads (x-pitched padded buffers => provable alignment).
// Decoder ConvT stays bf16 MFMA implicit GEMM (proven in R2).
// Latent path stays fp32 => VQ argmin indices exact.
// ---------------------------------------------------------------------------

using f32x4  = __attribute__((ext_vector_type(4))) float;
using bf16x8 = __attribute__((ext_vector_type(8))) short;

__device__ __forceinline__ unsigned short f32_to_bf16(float f) {
    unsigned int u = __float_as_uint(f);
    u += 0x7fffu + ((u >> 16) & 1u);          // round-to-nearest-even
    return (unsigned short)(u >> 16);
}
__device__ __forceinline__ void store_act(float* p, float v) { *p = v; }
__device__ __forceinline__ void store_act(unsigned short* p, float v) { *p = f32_to_bf16(v); }

// ---------------- padding / halo utilities ----------------
// Pitched pad: xp (BC, PD, PD, PRX); halo + pitch extras zeroed.
__global__ __launch_bounds__(256)
void pad_input_p(const float* __restrict__ x, float* __restrict__ xp,
                 int BC, int D, int PRX)
{
    int PD = D + 2;
    long total = (long)BC * PD * PD * PRX;
    long idx = (long)blockIdx.x * blockDim.x + threadIdx.x;
    if (idx >= total) return;
    int px = (int)(idx % PRX); long t = idx / PRX;
    int py = (int)(t % PD); t /= PD;
    int pz = (int)(t % PD); int c = (int)(t / PD);
    int ix = px - 1, iy = py - 1, iz = pz - 1;
    float v = 0.0f;
    if ((unsigned)ix < (unsigned)D && (unsigned)iy < (unsigned)D && (unsigned)iz < (unsigned)D)
        v = x[(((long)c * D + iz) * D + iy) * D + ix];
    xp[idx] = v;
}

// Zero halo cells of pitched (C, PD, PD, PRX) fp32 buffer (incl. pitch extras).
__global__ __launch_bounds__(256)
void zero_halo_p(float* __restrict__ p, int C, int PD, int PRX)
{
    long total = (long)C * PD * PD * PRX;
    long idx = (long)blockIdx.x * blockDim.x + threadIdx.x;
    if (idx >= total) return;
    int px = (int)(idx % PRX); long t = idx / PRX;
    int py = (int)(t % PD); t /= PD;
    int pz = (int)(t % PD);
    if (px == 0 || px >= PD - 1 || py == 0 || py == PD - 1 || pz == 0 || pz == PD - 1)
        p[idx] = 0.0f;
}

// Unpitched halo zero (bf16 decoder activations).
template <typename T>
__global__ __launch_bounds__(256) void zero_halo_t(T* __restrict__ p, int C, int PD)
{
    long total = (long)C * PD * PD * PD;
    long idx = (long)blockIdx.x * blockDim.x + threadIdx.x;
    if (idx >= total) return;
    int px = (int)(idx % PD); long t = idx / PD;
    int py = (int)(t % PD); t /= PD;
    int pz = (int)(t % PD);
    if (px == 0 || px == PD - 1 || py == 0 || py == PD - 1 || pz == 0 || pz == PD - 1)
        p[idx] = (T)0;
}

// ---------------- vector row load (alignment guaranteed by pitch) ----------
template <int S>
__device__ __forceinline__ void load_row(const float* __restrict__ p, float* v) {
    if constexpr (S == 6) {
        *(float4*)v = *(const float4*)p;
        *(float2*)(v + 4) = *(const float2*)(p + 4);
    } else if constexpr (S == 10) {
        *(float4*)v = *(const float4*)p;
        *(float4*)(v + 4) = *(const float4*)(p + 4);
        *(float2*)(v + 8) = *(const float2*)(p + 8);
    }
}

// ---------------------------------------------------------------------------
// Strided conv k=4 s=2 p=1 (+ReLU), (TZ,TY,TX) output tile per thread.
// xp: (B,Cin,PD,PD,PRX) pitched padded. w: (Cout,Cin,64). co wave-uniform.
// y: (B,Cout,OPD,OPD,OPRX), interior written at +po.
// Tap rule: padded input jz (tile-local) feeds output oz with kz = jz-2*oz.
// ---------------------------------------------------------------------------
template <int TZ, int TY, int TX>
__global__ __launch_bounds__(256)
void conv_s2_tile(const float* __restrict__ xp, const float* __restrict__ wgt,
                  const float* __restrict__ bias, float* __restrict__ y,
                  int B, int Cin, int Cout, int Dout, int PD, int PRX,
                  int chunks, int OPD, int OPRX, int po)
{
    constexpr int SZ = 2 * TZ + 2, SY = 2 * TY + 2, SX = 2 * TX + 2;
    const int NTX = Dout / TX, NTY = Dout / TY, NTZ = Dout / TZ;
    const int NT = NTX * NTY * NTZ;
    int bx = blockIdx.x;
    const int chunk = bx % chunks; bx /= chunks;
    const int co = bx % Cout;                 // wave-uniform
    const int b  = bx / Cout;
    const int tile = chunk * 256 + (int)threadIdx.x;
    if (tile >= NT) return;
    const int tx = tile % NTX, ty = (tile / NTX) % NTY, tz = tile / (NTX * NTY);
    const int ibz = 2 * TZ * tz, iby = 2 * TY * ty, ibx = 2 * TX * tx;
    const long chs = (long)PD * PD * PRX;
    const float* xb = xp + (long)b * Cin * chs + ((long)ibz * PD + iby) * PRX + ibx;
    const float* wb = wgt + (long)co * Cin * 64;

    const float bv = bias[co];
    float acc[TZ][TY][TX];
    #pragma unroll
    for (int a = 0; a < TZ; ++a)
        #pragma unroll
        for (int c = 0; c < TY; ++c)
            #pragma unroll
            for (int d = 0; d < TX; ++d) acc[a][c][d] = bv;

    for (int ci = 0; ci < Cin; ++ci) {
        const float* wr = wb + ci * 64;        // uniform -> s_load
        const float* xc = xb + ci * chs;
        #pragma unroll
        for (int jz = 0; jz < SZ; ++jz) {
            float plane[SY][SX];
            #pragma unroll
            for (int jy = 0; jy < SY; ++jy)
                load_row<SX>(xc + ((long)jz * PD + jy) * PRX, plane[jy]);
            #pragma unroll
            for (int oz = 0; oz < TZ; ++oz) {
                const int kz = jz - 2 * oz;
                if (kz < 0 || kz > 3) continue;
                #pragma unroll
                for (int jy = 0; jy < SY; ++jy) {
                    #pragma unroll
                    for (int oy = 0; oy < TY; ++oy) {
                        const int ky = jy - 2 * oy;
                        if (ky < 0 || ky > 3) continue;
                        #pragma unroll
                        for (int jx = 0; jx < SX; ++jx) {
                            #pragma unroll
                            for (int ox = 0; ox < TX; ++ox) {
                                const int kx = jx - 2 * ox;
                                if (kx < 0 || kx > 3) continue;
                                acc[oz][oy][ox] = fmaf(plane[jy][jx],
                                                       wr[(kz * 4 + ky) * 4 + kx],
                                                       acc[oz][oy][ox]);
                            }
                        }
                    }
                }
            }
        }
    }

    float* yb = y + (long)(b * Cout + co) * OPD * OPD * OPRX;
    #pragma unroll
    for (int oz = 0; oz < TZ; ++oz)
        #pragma unroll
        for (int oy = 0; oy < TY; ++oy)
            #pragma unroll
            for (int ox = 0; ox < TX; ++ox) {
                int opz = TZ * tz + oz + po, opy = TY * ty + oy + po, opx = TX * tx + ox + po;
                yb[((long)opz * OPD + opy) * OPRX + opx] = fmaxf(acc[oz][oy][ox], 0.0f);
            }
}

// ---------------- 1x1 conv: co wave-uniform, float4 spatial -----------------
// x:(B,256,512) h3. y:(B,256,512) lat. grid = B*256 blocks of 128 threads.
__global__ __launch_bounds__(128)
void conv1x1_b(const float* __restrict__ x, const float* __restrict__ w,
               const float* __restrict__ bias, float* __restrict__ y)
{
    const int co = blockIdx.x & 255, b = blockIdx.x >> 8;
    const int s4 = (int)threadIdx.x * 4;
    const float* xb = x + (long)b * 256 * 512 + s4;
    const float* wr = w + (long)co * 256;      // uniform -> s_load
    float bv = bias[co];
    float4 acc = {bv, bv, bv, bv};
    for (int ci = 0; ci < 256; ++ci) {
        float wv = wr[ci];
        float4 xv = *(const float4*)(xb + (long)ci * 512);
        acc.x = fmaf(xv.x, wv, acc.x); acc.y = fmaf(xv.y, wv, acc.y);
        acc.z = fmaf(xv.z, wv, acc.z); acc.w = fmaf(xv.w, wv, acc.w);
    }
    *(float4*)(y + (long)(b * 256 + co) * 512 + s4) = acc;
}

// ---------------- VQ (fp32 exact; same summation order as R2) ----------------
__global__ void codenorm_kernel(const float* __restrict__ cb, float* __restrict__ norms)
{
    int k = blockIdx.x;
    int lane = threadIdx.x;
    float s = 0.0f;
    const float* row = cb + (long)k * 256;
    for (int d = lane; d < 256; d += 64) { float v = row[d]; s = fmaf(v, v, s); }
    for (int off = 32; off > 0; off >>= 1) s += __shfl_down(s, off);
    if (lane == 0) norms[k] = s;
}

__global__ __launch_bounds__(256)
void vq_kernel(const float* __restrict__ lat, const float* __restrict__ cb,
               const float* __restrict__ norms, unsigned short* __restrict__ q,
               float* __restrict__ idx_out)
{
    __shared__ __align__(16) float row[256];
    __shared__ float s_best[256];
    __shared__ int   s_bidx[256];
    int r = blockIdx.x;
    int t = threadIdx.x;
    row[t] = lat[(long)r * 256 + t];
    __syncthreads();

    const float4* rowv = (const float4*)row;
    float latn = 0.0f;
    #pragma unroll 4
    for (int d = 0; d < 64; ++d) {
        float4 rv = rowv[d];
        latn = fmaf(rv.x, rv.x, latn); latn = fmaf(rv.y, rv.y, latn);
        latn = fmaf(rv.z, rv.z, latn); latn = fmaf(rv.w, rv.w, latn);
    }

    float best = FLT_MAX;
    int bidx = 0x7fffffff;
    for (int j = 0; j < 4; ++j) {
        int k = t + 256 * j;
        const float4* cr = (const float4*)(cb + (long)k * 256);
        float dot = 0.0f;
        #pragma unroll 4
        for (int d = 0; d < 64; ++d) {
            float4 c = cr[d]; float4 rv = rowv[d];
            dot = fmaf(rv.x, c.x, dot); dot = fmaf(rv.y, c.y, dot);
            dot = fmaf(rv.z, c.z, dot); dot = fmaf(rv.w, c.w, dot);
        }
        float sc = latn - 2.0f * dot + norms[k];
        if (sc < best || (sc == best && k < bidx)) { best = sc; bidx = k; }
    }
    s_best[t] = best; s_bidx[t] = bidx;
    __syncthreads();
    for (int off = 128; off > 0; off >>= 1) {
        if (t < off) {
            float o = s_best[t + off]; int oi = s_bidx[t + off];
            if (o < s_best[t] || (o == s_best[t] && oi < s_bidx[t])) {
                s_best[t] = o; s_bidx[t] = oi;
            }
        }
        __syncthreads();
    }
    int bk = s_bidx[0];
    int b = r >> 9, n = r & 511;
    int zz = n >> 6, yy = (n >> 3) & 7, xx = n & 7;
    q[(long)(b * 256 + t) * 1000 + ((long)(zz + 1) * 10 + (yy + 1)) * 10 + (xx + 1)]
        = f32_to_bf16(cb[(long)bk * 256 + t]);
    if (t == 0) idx_out[r] = (float)bk;
}

// ---------------- decoder: MFMA implicit-GEMM ConvTranspose ----------------
__global__ __launch_bounds__(256)
void prep_convt_w(const float* __restrict__ w, short* __restrict__ Ap,
                  int Cin, int Cout)
{
    const int K = Cin * 8;
    long total = 8L * Cout * K;
    long idx = (long)blockIdx.x * blockDim.x + threadIdx.x;
    if (idx >= total) return;
    int k = (int)(idx % K);
    int co = (int)((idx / K) % Cout);
    int p = (int)(idx / ((long)K * Cout));
    int ci = k >> 3, a = k & 7;
    int az = (a >> 2) & 1, ay = (a >> 1) & 1, ax = a & 1;
    int pz = p >> 2, py = (p >> 1) & 1, px = p & 1;
    int kd = (1 - pz) + 2 * az, kh = (1 - py) + 2 * ay, kw = (1 - px) + 2 * ax;
    float v = w[((long)ci * Cout + co) * 64 + kd * 16 + kh * 4 + kw];
    Ap[idx] = (short)f32_to_bf16(v);
}

// OPAD: 1 => padded output (next layer is convt), 0 => tight Dout^3 output.
template <int DIN, int OPAD, typename OutT>
__global__ __launch_bounds__(256)
void convt_mfma(const unsigned short* __restrict__ Xp, const short* __restrict__ Ap,
                const float* __restrict__ bias, OutT* __restrict__ Y,
                int Cin, int Cout)
{
    constexpr int PD = DIN + 2;
    constexpr int PD3 = PD * PD * PD;
    constexpr int T = DIN >> 2;
    constexpr int NT = T * T * T;
    constexpr int OPD = 2 * DIN + 2 * OPAD;
    const int K = Cin * 8;
    const int MG = Cout >> 6;

    int bx = blockIdx.x;
    const int mg = bx % MG; bx /= MG;
    const int nt = bx % NT; bx /= NT;
    const int p = bx;
    const int pz = p >> 2, py = (p >> 1) & 1, px = p & 1;

    const int lane = threadIdx.x & 63, wave = threadIdx.x >> 6;
    const int n16 = lane & 15, quad = lane >> 4;

    const int tx = nt % T, ty = (nt / T) % T, tz = nt / (T * T);
    const int mz = tz * 4 + wave, my = ty * 4 + (n16 >> 2), mx = tx * 4 + (n16 & 3);
    const int sp = ((mz + pz) * PD + (my + py)) * PD + (mx + px);

    const unsigned short* xq = Xp + (long)quad * PD3 + sp;

    const int cobase = mg * 64;
    const short* ap0 = Ap + ((long)p * Cout + cobase + n16) * K + quad * 8;

    f32x4 acc[4];
    #pragma unroll
    for (int cb = 0; cb < 4; ++cb) {
        const float* bp = bias + cobase + cb * 16 + quad * 4;
        acc[cb][0] = bp[0]; acc[cb][1] = bp[1]; acc[cb][2] = bp[2]; acc[cb][3] = bp[3];
    }

    const int nsteps = K >> 5;
    for (int s = 0; s < nsteps; ++s) {
        bf16x8 bf;
        bf[0] = (short)xq[(PD + 1) * PD + 1];
        bf[1] = (short)xq[(PD + 1) * PD];
        bf[2] = (short)xq[PD * PD + 1];
        bf[3] = (short)xq[PD * PD];
        bf[4] = (short)xq[PD + 1];
        bf[5] = (short)xq[PD];
        bf[6] = (short)xq[1];
        bf[7] = (short)xq[0];
        #pragma unroll
        for (int cb = 0; cb < 4; ++cb) {
            bf16x8 af = *(const bf16x8*)(ap0 + (long)cb * 16 * K + s * 32);
            acc[cb] = __builtin_amdgcn_mfma_f32_16x16x32_bf16(af, bf, acc[cb], 0, 0, 0);
        }
        xq += 4 * PD3;
    }

    const int opz = 2 * mz + pz + OPAD, opy = 2 * my + py + OPAD, opx = 2 * mx + px + OPAD;
    const long spo = ((long)opz * OPD + opy) * OPD + opx;
    #pragma unroll
    for (int cb = 0; cb < 4; ++cb) {
        #pragma unroll
        for (int r = 0; r < 4; ++r) {
            int co = cobase + cb * 16 + quad * 4 + r;
            float v = fmaxf(acc[cb][r], 0.0f);
            store_act(Y + (long)co * OPD * OPD * OPD + spo, v);
        }
    }
}

// ---------------- final conv k4 s1 p0 + tanh, (2,2,2) tile, fp32 ------------
// x: (64, 64^3) UNPADDED fp32. y: (3, 61^3). grid = 3*117 per batch.
__global__ __launch_bounds__(256)
void conv_dec4_t2(const float* __restrict__ x, const float* __restrict__ wgt,
                  const float* __restrict__ bias, float* __restrict__ y)
{
    constexpr int D = 64, Dout = 61, Cin = 64, NT = 31;
    int bx = blockIdx.x;
    const int chunk = bx % 117;
    const int co = bx / 117;                   // wave-uniform
    const int tile = chunk * 256 + (int)threadIdx.x;
    if (tile >= NT * NT * NT) return;
    const int tx = tile % NT, ty = (tile / NT) % NT, tz = tile / (NT * NT);

    int zo[5], yo[5];
    #pragma unroll
    for (int j = 0; j < 5; ++j) {
        zo[j] = min(2 * tz + j, D - 1) * D * D;   // clamped: OOB planes only feed invalid outputs
        yo[j] = min(2 * ty + j, D - 1) * D;
    }
    const int ibx = 2 * tx;                    // span [ibx, ibx+4]; 8B-aligned base

    const float bv = bias[co];
    float acc[2][2][2];
    #pragma unroll
    for (int a = 0; a < 2; ++a)
        #pragma unroll
        for (int c = 0; c < 2; ++c)
            #pragma unroll
            for (int d = 0; d < 2; ++d) acc[a][c][d] = bv;

    const float* wb = wgt + (long)co * Cin * 64;
    for (int ci = 0; ci < Cin; ++ci) {
        const float* wr = wb + ci * 64;        // uniform -> s_load
        const float* xc = x + (long)ci * D * D * D + ibx;
        #pragma unroll
        for (int jz = 0; jz < 5; ++jz) {
            float plane[5][5];
            #pragma unroll
            for (int jy = 0; jy < 5; ++jy) {
                const float* rp = xc + zo[jz] + yo[jy];
                *(float2*)plane[jy] = *(const float2*)rp;
                *(float2*)(plane[jy] + 2) = *(const float2*)(rp + 2);
                plane[jy][4] = rp[4];
            }
            #pragma unroll
            for (int oz = 0; oz < 2; ++oz) {
                const int kz = jz - oz;
                if (kz < 0 || kz > 3) continue;
                #pragma unroll
                for (int jy = 0; jy < 5; ++jy) {
                    #pragma unroll
                    for (int oy = 0; oy < 2; ++oy) {
                        const int ky = jy - oy;
                        if (ky < 0 || ky > 3) continue;
                        #pragma unroll
                        for (int jx = 0; jx < 5; ++jx) {
                            #pragma unroll
                            for (int ox = 0; ox < 2; ++ox) {
                                const int kx = jx - ox;
                                if (kx < 0 || kx > 3) continue;
                                acc[oz][oy][ox] = fmaf(plane[jy][jx],
                                                       wr[(kz * 4 + ky) * 4 + kx],
                                                       acc[oz][oy][ox]);
                            }
                        }
                    }
                }
            }
        }
    }

    #pragma unroll
    for (int oz = 0; oz < 2; ++oz) {
        const int od = 2 * tz + oz; if (od >= Dout) continue;
        #pragma unroll
        for (int oy = 0; oy < 2; ++oy) {
            const int oh = 2 * ty + oy; if (oh >= Dout) continue;
            #pragma unroll
            for (int ox = 0; ox < 2; ++ox) {
                const int ow = 2 * tx + ox; if (ow >= Dout) continue;
                y[((long)(co * Dout + od) * Dout + oh) * Dout + ow] = tanhf(acc[oz][oy][ox]);
            }
        }
    }
}

extern "C" void kernel_launch(void* const* d_in, const int* in_sizes, int n_in,
                              void* d_out, int out_size, void* d_ws, size_t ws_size,
                              hipStream_t stream)
{
    const float* x        = (const float*)d_in[0];
    const float* enc_w1   = (const float*)d_in[1];
    const float* enc_b1   = (const float*)d_in[2];
    const float* enc_w2   = (const float*)d_in[3];
    const float* enc_b2   = (const float*)d_in[4];
    const float* enc_w3   = (const float*)d_in[5];
    const float* enc_b3   = (const float*)d_in[6];
    const float* enc_w4   = (const float*)d_in[7];
    const float* enc_b4   = (const float*)d_in[8];
    const float* codebook = (const float*)d_in[9];
    const float* dec_w1   = (const float*)d_in[10];
    const float* dec_b1   = (const float*)d_in[11];
    const float* dec_w2   = (const float*)d_in[12];
    const float* dec_b2   = (const float*)d_in[13];
    const float* dec_w3   = (const float*)d_in[14];
    const float* dec_b3   = (const float*)d_in[15];
    const float* dec_w4   = (const float*)d_in[16];
    const float* dec_b4   = (const float*)d_in[17];

    float* out = (float*)d_out;
    float* idx_out = out + 2L * 3 * 61 * 61 * 61;

    // ---- workspace (byte offsets; persistent | overlapped arena) ----
    char* wsb = (char*)d_ws;
    float*          cn  = (float*)wsb;                       //     4,096 B
    unsigned short* qp  = (unsigned short*)(wsb + 4096);     // 1,024,000 B
    short*          Ap1 = (short*)(wsb + 1028096);           // 8,388,608 B
    short*          Ap2 = (short*)(wsb + 9416704);           // 4,194,304 B
    short*          Ap3 = (short*)(wsb + 13611008);          // 1,048,576 B
    char* arena = wsb + 14659584;
    // encoder phase (fp32, x-pitched padded):
    float* xp  = (float*)arena;                  // (2,3,66,66,68)  = 1,777,248 f
    float* h1p = (float*)arena + 1777248;        // (2,64,34,34,36) = 5,326,848 f
    float* h2p = (float*)arena + 7104096;        // (2,128,18,18,20)= 1,658,880 f
    float* h3  = (float*)arena + 8762976;        // (2,256,8^3)     =   262,144 f
    float* lat = (float*)arena + 9025120;        //                   262,144 f (end 9,287,264 f)
    // decoder phase (after VQ; overlaps encoder buffers):
    unsigned short* d1 = (unsigned short*)arena;               // (256,18^3) bf16 = 2,985,984 B
    unsigned short* d2 = (unsigned short*)(arena + 2985984);   // (128,34^3) bf16 = 10,061,824 B
    float*          d3 = (float*)(arena + 13047808);           // (64,64^3) fp32  = 67,108,864 B
    // arena peak 80.2 MB; total ~94.9 MB (<101.3 MB proven in R2)

    dim3 blk(256);
    auto nblk = [](long n) { return dim3((unsigned)((n + 255) / 256)); };

    // ---- decoder weight pre-gather ----
    prep_convt_w<<<nblk(8L * 256 * 2048), blk, 0, stream>>>(dec_w1, Ap1, 256, 256);
    prep_convt_w<<<nblk(8L * 128 * 2048), blk, 0, stream>>>(dec_w2, Ap2, 256, 128);
    prep_convt_w<<<nblk(8L * 64 * 1024), blk, 0, stream>>>(dec_w3, Ap3, 128, 64);

    // ---- encoder (fp32, pitched) ----
    pad_input_p<<<nblk(6L * 66 * 66 * 68), blk, 0, stream>>>(x, xp, 6, 64, 68);
    zero_halo_p<<<nblk(128L * 34 * 34 * 36), blk, 0, stream>>>(h1p, 128, 34, 36);
    // enc1: Cin=3 Cout=64 Dout=32, tile(2,2,4): NT=2048, chunks=8, grid=1024
    conv_s2_tile<2, 2, 4><<<dim3(2 * 64 * 8), blk, 0, stream>>>(
        xp, enc_w1, enc_b1, h1p, 2, 3, 64, 32, 66, 68, 8, 34, 36, 1);
    zero_halo_p<<<nblk(256L * 18 * 18 * 20), blk, 0, stream>>>(h2p, 256, 18, 20);
    // enc2: Cin=64 Cout=128 Dout=16, tile(1,2,2): NT=1024, chunks=4, grid=1024
    conv_s2_tile<1, 2, 2><<<dim3(2 * 128 * 4), blk, 0, stream>>>(
        h1p, enc_w2, enc_b2, h2p, 2, 64, 128, 16, 34, 36, 4, 18, 20, 1);
    // enc3: Cin=128 Cout=256 Dout=8, tile(1,1,2): NT=256, chunks=1, grid=512; tight out
    conv_s2_tile<1, 1, 2><<<dim3(2 * 256), blk, 0, stream>>>(
        h2p, enc_w3, enc_b3, h3, 2, 128, 256, 8, 18, 20, 1, 8, 8, 0);
    // enc4 (1x1): grid = 2*256 blocks of 128
    conv1x1_b<<<dim3(512), dim3(128), 0, stream>>>(h3, enc_w4, enc_b4, lat);

    // ---- VQ (fp32 exact) ----
    codenorm_kernel<<<dim3(1024), dim3(64), 0, stream>>>(codebook, cn);
    zero_halo_t<unsigned short><<<nblk(512L * 10 * 10 * 10), blk, 0, stream>>>(qp, 512, 10);
    vq_kernel<<<dim3(1024), blk, 0, stream>>>(lat, codebook, cn, qp, idx_out);

    // ---- decoder halos (after VQ: d1/d2 overlap encoder buffers) ----
    zero_halo_t<unsigned short><<<nblk(256L * 18 * 18 * 18), blk, 0, stream>>>(d1, 256, 18);
    zero_halo_t<unsigned short><<<nblk(128L * 34 * 34 * 34), blk, 0, stream>>>(d2, 128, 34);

    // ---- decoder (MFMA) per batch ----
    for (int b = 0; b < 2; ++b) {
        const unsigned short* qb = qp + (long)b * 256 * 1000;
        float* outb = out + (long)b * 3 * 226981;
        convt_mfma<8, 1, unsigned short><<<dim3(8 * 8 * 4), blk, 0, stream>>>(
            qb, Ap1, dec_b1, d1, 256, 256);
        convt_mfma<16, 1, unsigned short><<<dim3(8 * 64 * 2), blk, 0, stream>>>(
            d1, Ap2, dec_b2, d2, 256, 128);
        convt_mfma<32, 0, float><<<dim3(8 * 512), blk, 0, stream>>>(
            d2, Ap3, dec_b3, d3, 128, 64);
        conv_dec4_t2<<<dim3(3 * 117), blk, 0, stream>>>(d3, dec_w4, dec_b4, outb);
    }
}

// Round 5
// 2818.348 us; speedup vs baseline: 8.8447x; 1.1147x over previous
//
#include <hip/hip_runtime.h>
#include <cfloat>
#include <cmath>

// ---------------------------------------------------------------------------
// Round 4: dec4 (final conv k4 s1 p0 + tanh) -> MFMA implicit GEMM
// (M=16 rows, 3 used; N=61^3; K=4096). Fixes the 242 MB re-fetch + latency
// bound of the VALU dec4. Encoder/VQ/dec1-3 unchanged from R3.
// ---------------------------------------------------------------------------

using f32x4  = __attribute__((ext_vector_type(4))) float;
using bf16x8 = __attribute__((ext_vector_type(8))) short;
typedef float f32x4u __attribute__((ext_vector_type(4), aligned(4)));  // 4B-aligned vec load

__device__ __forceinline__ unsigned short f32_to_bf16(float f) {
    unsigned int u = __float_as_uint(f);
    u += 0x7fffu + ((u >> 16) & 1u);          // round-to-nearest-even
    return (unsigned short)(u >> 16);
}
__device__ __forceinline__ void store_act(float* p, float v) { *p = v; }
__device__ __forceinline__ void store_act(unsigned short* p, float v) { *p = f32_to_bf16(v); }

// ---------------- padding / halo utilities ----------------
__global__ __launch_bounds__(256)
void pad_input_p(const float* __restrict__ x, float* __restrict__ xp,
                 int BC, int D, int PRX)
{
    int PD = D + 2;
    long total = (long)BC * PD * PD * PRX;
    long idx = (long)blockIdx.x * blockDim.x + threadIdx.x;
    if (idx >= total) return;
    int px = (int)(idx % PRX); long t = idx / PRX;
    int py = (int)(t % PD); t /= PD;
    int pz = (int)(t % PD); int c = (int)(t / PD);
    int ix = px - 1, iy = py - 1, iz = pz - 1;
    float v = 0.0f;
    if ((unsigned)ix < (unsigned)D && (unsigned)iy < (unsigned)D && (unsigned)iz < (unsigned)D)
        v = x[(((long)c * D + iz) * D + iy) * D + ix];
    xp[idx] = v;
}

__global__ __launch_bounds__(256)
void zero_halo_p(float* __restrict__ p, int C, int PD, int PRX)
{
    long total = (long)C * PD * PD * PRX;
    long idx = (long)blockIdx.x * blockDim.x + threadIdx.x;
    if (idx >= total) return;
    int px = (int)(idx % PRX); long t = idx / PRX;
    int py = (int)(t % PD); t /= PD;
    int pz = (int)(t % PD);
    if (px == 0 || px >= PD - 1 || py == 0 || py == PD - 1 || pz == 0 || pz == PD - 1)
        p[idx] = 0.0f;
}

template <typename T>
__global__ __launch_bounds__(256) void zero_halo_t(T* __restrict__ p, int C, int PD)
{
    long total = (long)C * PD * PD * PD;
    long idx = (long)blockIdx.x * blockDim.x + threadIdx.x;
    if (idx >= total) return;
    int px = (int)(idx % PD); long t = idx / PD;
    int py = (int)(t % PD); t /= PD;
    int pz = (int)(t % PD);
    if (px == 0 || px == PD - 1 || py == 0 || py == PD - 1 || pz == 0 || pz == PD - 1)
        p[idx] = (T)0;
}

// ---------------- vector row load (alignment guaranteed by pitch) ----------
template <int S>
__device__ __forceinline__ void load_row(const float* __restrict__ p, float* v) {
    if constexpr (S == 6) {
        *(float4*)v = *(const float4*)p;
        *(float2*)(v + 4) = *(const float2*)(p + 4);
    } else if constexpr (S == 10) {
        *(float4*)v = *(const float4*)p;
        *(float4*)(v + 4) = *(const float4*)(p + 4);
        *(float2*)(v + 8) = *(const float2*)(p + 8);
    }
}

// ---------------------------------------------------------------------------
// Strided conv k=4 s=2 p=1 (+ReLU), (TZ,TY,TX) output tile per thread.
// ---------------------------------------------------------------------------
template <int TZ, int TY, int TX>
__global__ __launch_bounds__(256)
void conv_s2_tile(const float* __restrict__ xp, const float* __restrict__ wgt,
                  const float* __restrict__ bias, float* __restrict__ y,
                  int B, int Cin, int Cout, int Dout, int PD, int PRX,
                  int chunks, int OPD, int OPRX, int po)
{
    constexpr int SZ = 2 * TZ + 2, SY = 2 * TY + 2, SX = 2 * TX + 2;
    const int NTX = Dout / TX, NTY = Dout / TY, NTZ = Dout / TZ;
    const int NT = NTX * NTY * NTZ;
    int bx = blockIdx.x;
    const int chunk = bx % chunks; bx /= chunks;
    const int co = bx % Cout;                 // wave-uniform
    const int b  = bx / Cout;
    const int tile = chunk * 256 + (int)threadIdx.x;
    if (tile >= NT) return;
    const int tx = tile % NTX, ty = (tile / NTX) % NTY, tz = tile / (NTX * NTY);
    const int ibz = 2 * TZ * tz, iby = 2 * TY * ty, ibx = 2 * TX * tx;
    const long chs = (long)PD * PD * PRX;
    const float* xb = xp + (long)b * Cin * chs + ((long)ibz * PD + iby) * PRX + ibx;
    const float* wb = wgt + (long)co * Cin * 64;

    const float bv = bias[co];
    float acc[TZ][TY][TX];
    #pragma unroll
    for (int a = 0; a < TZ; ++a)
        #pragma unroll
        for (int c = 0; c < TY; ++c)
            #pragma unroll
            for (int d = 0; d < TX; ++d) acc[a][c][d] = bv;

    for (int ci = 0; ci < Cin; ++ci) {
        const float* wr = wb + ci * 64;        // uniform -> s_load
        const float* xc = xb + ci * chs;
        #pragma unroll
        for (int jz = 0; jz < SZ; ++jz) {
            float plane[SY][SX];
            #pragma unroll
            for (int jy = 0; jy < SY; ++jy)
                load_row<SX>(xc + ((long)jz * PD + jy) * PRX, plane[jy]);
            #pragma unroll
            for (int oz = 0; oz < TZ; ++oz) {
                const int kz = jz - 2 * oz;
                if (kz < 0 || kz > 3) continue;
                #pragma unroll
                for (int jy = 0; jy < SY; ++jy) {
                    #pragma unroll
                    for (int oy = 0; oy < TY; ++oy) {
                        const int ky = jy - 2 * oy;
                        if (ky < 0 || ky > 3) continue;
                        #pragma unroll
                        for (int jx = 0; jx < SX; ++jx) {
                            #pragma unroll
                            for (int ox = 0; ox < TX; ++ox) {
                                const int kx = jx - 2 * ox;
                                if (kx < 0 || kx > 3) continue;
                                acc[oz][oy][ox] = fmaf(plane[jy][jx],
                                                       wr[(kz * 4 + ky) * 4 + kx],
                                                       acc[oz][oy][ox]);
                            }
                        }
                    }
                }
            }
        }
    }

    float* yb = y + (long)(b * Cout + co) * OPD * OPD * OPRX;
    #pragma unroll
    for (int oz = 0; oz < TZ; ++oz)
        #pragma unroll
        for (int oy = 0; oy < TY; ++oy)
            #pragma unroll
            for (int ox = 0; ox < TX; ++ox) {
                int opz = TZ * tz + oz + po, opy = TY * ty + oy + po, opx = TX * tx + ox + po;
                yb[((long)opz * OPD + opy) * OPRX + opx] = fmaxf(acc[oz][oy][ox], 0.0f);
            }
}

// ---------------- 1x1 conv ----------------
__global__ __launch_bounds__(128)
void conv1x1_b(const float* __restrict__ x, const float* __restrict__ w,
               const float* __restrict__ bias, float* __restrict__ y)
{
    const int co = blockIdx.x & 255, b = blockIdx.x >> 8;
    const int s4 = (int)threadIdx.x * 4;
    const float* xb = x + (long)b * 256 * 512 + s4;
    const float* wr = w + (long)co * 256;      // uniform -> s_load
    float bv = bias[co];
    float4 acc = {bv, bv, bv, bv};
    for (int ci = 0; ci < 256; ++ci) {
        float wv = wr[ci];
        float4 xv = *(const float4*)(xb + (long)ci * 512);
        acc.x = fmaf(xv.x, wv, acc.x); acc.y = fmaf(xv.y, wv, acc.y);
        acc.z = fmaf(xv.z, wv, acc.z); acc.w = fmaf(xv.w, wv, acc.w);
    }
    *(float4*)(y + (long)(b * 256 + co) * 512 + s4) = acc;
}

// ---------------- VQ (fp32 exact; same summation order as R2/R3) ------------
__global__ void codenorm_kernel(const float* __restrict__ cb, float* __restrict__ norms)
{
    int k = blockIdx.x;
    int lane = threadIdx.x;
    float s = 0.0f;
    const float* row = cb + (long)k * 256;
    for (int d = lane; d < 256; d += 64) { float v = row[d]; s = fmaf(v, v, s); }
    for (int off = 32; off > 0; off >>= 1) s += __shfl_down(s, off);
    if (lane == 0) norms[k] = s;
}

__global__ __launch_bounds__(256)
void vq_kernel(const float* __restrict__ lat, const float* __restrict__ cb,
               const float* __restrict__ norms, unsigned short* __restrict__ q,
               float* __restrict__ idx_out)
{
    __shared__ __align__(16) float row[256];
    __shared__ float s_best[256];
    __shared__ int   s_bidx[256];
    int r = blockIdx.x;
    int t = threadIdx.x;
    row[t] = lat[(long)r * 256 + t];
    __syncthreads();

    const float4* rowv = (const float4*)row;
    float latn = 0.0f;
    #pragma unroll 4
    for (int d = 0; d < 64; ++d) {
        float4 rv = rowv[d];
        latn = fmaf(rv.x, rv.x, latn); latn = fmaf(rv.y, rv.y, latn);
        latn = fmaf(rv.z, rv.z, latn); latn = fmaf(rv.w, rv.w, latn);
    }

    float best = FLT_MAX;
    int bidx = 0x7fffffff;
    for (int j = 0; j < 4; ++j) {
        int k = t + 256 * j;
        const float4* cr = (const float4*)(cb + (long)k * 256);
        float dot = 0.0f;
        #pragma unroll 4
        for (int d = 0; d < 64; ++d) {
            float4 c = cr[d]; float4 rv = rowv[d];
            dot = fmaf(rv.x, c.x, dot); dot = fmaf(rv.y, c.y, dot);
            dot = fmaf(rv.z, c.z, dot); dot = fmaf(rv.w, c.w, dot);
        }
        float sc = latn - 2.0f * dot + norms[k];
        if (sc < best || (sc == best && k < bidx)) { best = sc; bidx = k; }
    }
    s_best[t] = best; s_bidx[t] = bidx;
    __syncthreads();
    for (int off = 128; off > 0; off >>= 1) {
        if (t < off) {
            float o = s_best[t + off]; int oi = s_bidx[t + off];
            if (o < s_best[t] || (o == s_best[t] && oi < s_bidx[t])) {
                s_best[t] = o; s_bidx[t] = oi;
            }
        }
        __syncthreads();
    }
    int bk = s_bidx[0];
    int b = r >> 9, n = r & 511;
    int zz = n >> 6, yy = (n >> 3) & 7, xx = n & 7;
    q[(long)(b * 256 + t) * 1000 + ((long)(zz + 1) * 10 + (yy + 1)) * 10 + (xx + 1)]
        = f32_to_bf16(cb[(long)bk * 256 + t]);
    if (t == 0) idx_out[r] = (float)bk;
}

// ---------------- decoder: MFMA implicit-GEMM ConvTranspose ----------------
__global__ __launch_bounds__(256)
void prep_convt_w(const float* __restrict__ w, short* __restrict__ Ap,
                  int Cin, int Cout)
{
    const int K = Cin * 8;
    long total = 8L * Cout * K;
    long idx = (long)blockIdx.x * blockDim.x + threadIdx.x;
    if (idx >= total) return;
    int k = (int)(idx % K);
    int co = (int)((idx / K) % Cout);
    int p = (int)(idx / ((long)K * Cout));
    int ci = k >> 3, a = k & 7;
    int az = (a >> 2) & 1, ay = (a >> 1) & 1, ax = a & 1;
    int pz = p >> 2, py = (p >> 1) & 1, px = p & 1;
    int kd = (1 - pz) + 2 * az, kh = (1 - py) + 2 * ay, kw = (1 - px) + 2 * ax;
    float v = w[((long)ci * Cout + co) * 64 + kd * 16 + kh * 4 + kw];
    Ap[idx] = (short)f32_to_bf16(v);
}

template <int DIN, int OPAD, typename OutT>
__global__ __launch_bounds__(256)
void convt_mfma(const unsigned short* __restrict__ Xp, const short* __restrict__ Ap,
                const float* __restrict__ bias, OutT* __restrict__ Y,
                int Cin, int Cout)
{
    constexpr int PD = DIN + 2;
    constexpr int PD3 = PD * PD * PD;
    constexpr int T = DIN >> 2;
    constexpr int NT = T * T * T;
    constexpr int OPD = 2 * DIN + 2 * OPAD;
    const int K = Cin * 8;
    const int MG = Cout >> 6;

    int bx = blockIdx.x;
    const int mg = bx % MG; bx /= MG;
    const int nt = bx % NT; bx /= NT;
    const int p = bx;
    const int pz = p >> 2, py = (p >> 1) & 1, px = p & 1;

    const int lane = threadIdx.x & 63, wave = threadIdx.x >> 6;
    const int n16 = lane & 15, quad = lane >> 4;

    const int tx = nt % T, ty = (nt / T) % T, tz = nt / (T * T);
    const int mz = tz * 4 + wave, my = ty * 4 + (n16 >> 2), mx = tx * 4 + (n16 & 3);
    const int sp = ((mz + pz) * PD + (my + py)) * PD + (mx + px);

    const unsigned short* xq = Xp + (long)quad * PD3 + sp;

    const int cobase = mg * 64;
    const short* ap0 = Ap + ((long)p * Cout + cobase + n16) * K + quad * 8;

    f32x4 acc[4];
    #pragma unroll
    for (int cb = 0; cb < 4; ++cb) {
        const float* bp = bias + cobase + cb * 16 + quad * 4;
        acc[cb][0] = bp[0]; acc[cb][1] = bp[1]; acc[cb][2] = bp[2]; acc[cb][3] = bp[3];
    }

    const int nsteps = K >> 5;
    for (int s = 0; s < nsteps; ++s) {
        bf16x8 bf;
        bf[0] = (short)xq[(PD + 1) * PD + 1];
        bf[1] = (short)xq[(PD + 1) * PD];
        bf[2] = (short)xq[PD * PD + 1];
        bf[3] = (short)xq[PD * PD];
        bf[4] = (short)xq[PD + 1];
        bf[5] = (short)xq[PD];
        bf[6] = (short)xq[1];
        bf[7] = (short)xq[0];
        #pragma unroll
        for (int cb = 0; cb < 4; ++cb) {
            bf16x8 af = *(const bf16x8*)(ap0 + (long)cb * 16 * K + s * 32);
            acc[cb] = __builtin_amdgcn_mfma_f32_16x16x32_bf16(af, bf, acc[cb], 0, 0, 0);
        }
        xq += 4 * PD3;
    }

    const int opz = 2 * mz + pz + OPAD, opy = 2 * my + py + OPAD, opx = 2 * mx + px + OPAD;
    const long spo = ((long)opz * OPD + opy) * OPD + opx;
    #pragma unroll
    for (int cb = 0; cb < 4; ++cb) {
        #pragma unroll
        for (int r = 0; r < 4; ++r) {
            int co = cobase + cb * 16 + quad * 4 + r;
            float v = fmaxf(acc[cb][r], 0.0f);
            store_act(Y + (long)co * OPD * OPD * OPD + spo, v);
        }
    }
}

// ---------------- dec4 as MFMA GEMM: M=16 (3 used), N=61^3, K=4096 ----------
// Aw[m][k] bf16: m<3 -> dec_w4[m*4096+k] (layout (3,64,64) = co,ci,tap), else 0.
__global__ __launch_bounds__(256)
void prep_dec4A(const float* __restrict__ w, short* __restrict__ Aw)
{
    int idx = blockIdx.x * 256 + (int)threadIdx.x;    // 0..65535
    int m = idx >> 12, k = idx & 4095;
    float v = (m < 3) ? w[m * 4096 + k] : 0.0f;
    Aw[idx] = (short)f32_to_bf16(v);
}

// d3: (64, 64^3) fp32 unpadded. y: (3, 61^3). Block = (od, oh), 4 waves over ow.
// Step s: ci = s>>1, tap-base = (s&1)*32 + quad*8 -> two x-consecutive float4
// spans of d3, truncated to bf16 in-register. A from Aw (L1-resident, 128 KB).
__global__ __launch_bounds__(256)
void conv_dec4_mfma(const float* __restrict__ d3, const short* __restrict__ Aw,
                    const float* __restrict__ bias, float* __restrict__ y)
{
    constexpr int D = 64, Dout = 61;
    const int oh = blockIdx.x % Dout, od = blockIdx.x / Dout;
    const int lane = (int)threadIdx.x & 63, wave = (int)threadIdx.x >> 6;
    const int n16 = lane & 15, quad = lane >> 4;
    const int ow = wave * 16 + n16;

    f32x4 acc;
    #pragma unroll
    for (int r = 0; r < 4; ++r) {
        int co = quad * 4 + r;
        acc[r] = (co < 3) ? bias[co] : 0.0f;
    }

    const short* ap = Aw + (long)n16 * 4096 + quad * 8;   // m = lane&15
    const int kd0 = quad >> 1;                 // tapb = quad*8: kd = tapb>>4
    const int kh0 = (quad & 1) * 2;            // kh = (tapb>>2)&3 in {0,2}
    const float* base0 = d3 + ((long)(od + kd0) * D + (oh + kh0)) * D + ow;

    #pragma unroll 4
    for (int s = 0; s < 128; ++s) {
        const int ci = s >> 1;
        // s even: kd = kd0, kh = kh0 ; s odd: kd = kd0+2, kh = kh0
        const float* base = base0 + ((long)ci * D + (s & 1) * 2) * D * D;
        f32x4u r0 = *(const f32x4u*)base;          // (kd, kh,   kw=0..3)
        f32x4u r1 = *(const f32x4u*)(base + D);    // (kd, kh+1, kw=0..3)
        bf16x8 bf;
        bf[0] = (short)(__float_as_uint(r0.x) >> 16);
        bf[1] = (short)(__float_as_uint(r0.y) >> 16);
        bf[2] = (short)(__float_as_uint(r0.z) >> 16);
        bf[3] = (short)(__float_as_uint(r0.w) >> 16);
        bf[4] = (short)(__float_as_uint(r1.x) >> 16);
        bf[5] = (short)(__float_as_uint(r1.y) >> 16);
        bf[6] = (short)(__float_as_uint(r1.z) >> 16);
        bf[7] = (short)(__float_as_uint(r1.w) >> 16);
        bf16x8 af = *(const bf16x8*)(ap + s * 32);
        acc = __builtin_amdgcn_mfma_f32_16x16x32_bf16(af, bf, acc, 0, 0, 0);
    }

    if (ow < Dout && quad == 0) {
        #pragma unroll
        for (int r = 0; r < 3; ++r)     // co = rows 0..2
            y[((long)(r * Dout + od) * Dout + oh) * Dout + ow] = tanhf(acc[r]);
    }
}

extern "C" void kernel_launch(void* const* d_in, const int* in_sizes, int n_in,
                              void* d_out, int out_size, void* d_ws, size_t ws_size,
                              hipStream_t stream)
{
    const float* x        = (const float*)d_in[0];
    const float* enc_w1   = (const float*)d_in[1];
    const float* enc_b1   = (const float*)d_in[2];
    const float* enc_w2   = (const float*)d_in[3];
    const float* enc_b2   = (const float*)d_in[4];
    const float* enc_w3   = (const float*)d_in[5];
    const float* enc_b3   = (const float*)d_in[6];
    const float* enc_w4   = (const float*)d_in[7];
    const float* enc_b4   = (const float*)d_in[8];
    const float* codebook = (const float*)d_in[9];
    const float* dec_w1   = (const float*)d_in[10];
    const float* dec_b1   = (const float*)d_in[11];
    const float* dec_w2   = (const float*)d_in[12];
    const float* dec_b2   = (const float*)d_in[13];
    const float* dec_w3   = (const float*)d_in[14];
    const float* dec_b3   = (const float*)d_in[15];
    const float* dec_w4   = (const float*)d_in[16];
    const float* dec_b4   = (const float*)d_in[17];

    float* out = (float*)d_out;
    float* idx_out = out + 2L * 3 * 61 * 61 * 61;

    // ---- workspace (byte offsets; persistent | overlapped arena) ----
    char* wsb = (char*)d_ws;
    float*          cn  = (float*)wsb;                       //     4,096 B
    unsigned short* qp  = (unsigned short*)(wsb + 4096);     // 1,024,000 B
    short*          Ap1 = (short*)(wsb + 1028096);           // 8,388,608 B
    short*          Ap2 = (short*)(wsb + 9416704);           // 4,194,304 B
    short*          Ap3 = (short*)(wsb + 13611008);          // 1,048,576 B
    short*          Aw4 = (short*)(wsb + 14659584);          //   131,072 B
    char* arena = wsb + 14790656;
    // encoder phase (fp32, x-pitched padded):
    float* xp  = (float*)arena;                  // (2,3,66,66,68)  = 1,777,248 f
    float* h1p = (float*)arena + 1777248;        // (2,64,34,34,36) = 5,326,848 f
    float* h2p = (float*)arena + 7104096;        // (2,128,18,18,20)= 1,658,880 f
    float* h3  = (float*)arena + 8762976;        // (2,256,8^3)     =   262,144 f
    float* lat = (float*)arena + 9025120;        //                   262,144 f
    // decoder phase (after VQ; overlaps encoder buffers):
    unsigned short* d1 = (unsigned short*)arena;               // (256,18^3) bf16
    unsigned short* d2 = (unsigned short*)(arena + 2985984);   // (128,34^3) bf16
    float*          d3 = (float*)(arena + 13047808);           // (64,64^3) fp32
    // arena peak 80.2 MB; total ~94.9 MB (< 112 MB proven in R0)

    dim3 blk(256);
    auto nblk = [](long n) { return dim3((unsigned)((n + 255) / 256)); };

    // ---- decoder weight pre-gather ----
    prep_convt_w<<<nblk(8L * 256 * 2048), blk, 0, stream>>>(dec_w1, Ap1, 256, 256);
    prep_convt_w<<<nblk(8L * 128 * 2048), blk, 0, stream>>>(dec_w2, Ap2, 256, 128);
    prep_convt_w<<<nblk(8L * 64 * 1024), blk, 0, stream>>>(dec_w3, Ap3, 128, 64);
    prep_dec4A<<<dim3(256), blk, 0, stream>>>(dec_w4, Aw4);

    // ---- encoder (fp32, pitched) ----
    pad_input_p<<<nblk(6L * 66 * 66 * 68), blk, 0, stream>>>(x, xp, 6, 64, 68);
    zero_halo_p<<<nblk(128L * 34 * 34 * 36), blk, 0, stream>>>(h1p, 128, 34, 36);
    conv_s2_tile<2, 2, 4><<<dim3(2 * 64 * 8), blk, 0, stream>>>(
        xp, enc_w1, enc_b1, h1p, 2, 3, 64, 32, 66, 68, 8, 34, 36, 1);
    zero_halo_p<<<nblk(256L * 18 * 18 * 20), blk, 0, stream>>>(h2p, 256, 18, 20);
    conv_s2_tile<1, 2, 2><<<dim3(2 * 128 * 4), blk, 0, stream>>>(
        h1p, enc_w2, enc_b2, h2p, 2, 64, 128, 16, 34, 36, 4, 18, 20, 1);
    conv_s2_tile<1, 1, 2><<<dim3(2 * 256), blk, 0, stream>>>(
        h2p, enc_w3, enc_b3, h3, 2, 128, 256, 8, 18, 20, 1, 8, 8, 0);
    conv1x1_b<<<dim3(512), dim3(128), 0, stream>>>(h3, enc_w4, enc_b4, lat);

    // ---- VQ (fp32 exact) ----
    codenorm_kernel<<<dim3(1024), dim3(64), 0, stream>>>(codebook, cn);
    zero_halo_t<unsigned short><<<nblk(512L * 10 * 10 * 10), blk, 0, stream>>>(qp, 512, 10);
    vq_kernel<<<dim3(1024), blk, 0, stream>>>(lat, codebook, cn, qp, idx_out);

    // ---- decoder halos ----
    zero_halo_t<unsigned short><<<nblk(256L * 18 * 18 * 18), blk, 0, stream>>>(d1, 256, 18);
    zero_halo_t<unsigned short><<<nblk(128L * 34 * 34 * 34), blk, 0, stream>>>(d2, 128, 34);

    // ---- decoder (MFMA) per batch ----
    for (int b = 0; b < 2; ++b) {
        const unsigned short* qb = qp + (long)b * 256 * 1000;
        float* outb = out + (long)b * 3 * 226981;
        convt_mfma<8, 1, unsigned short><<<dim3(8 * 8 * 4), blk, 0, stream>>>(
            qb, Ap1, dec_b1, d1, 256, 256);
        convt_mfma<16, 1, unsigned short><<<dim3(8 * 64 * 2), blk, 0, stream>>>(
            d1, Ap2, dec_b2, d2, 256, 128);
        convt_mfma<32, 0, float><<<dim3(8 * 512), blk, 0, stream>>>(
            d2, Ap3, dec_b3, d3, 128, 64);
        conv_dec4_mfma<<<dim3(61 * 61), blk, 0, stream>>>(d3, Aw4, dec_b4, outb);
    }
}